// Round 10
// baseline (245.330 us; speedup 1.0000x reference)
//
#include <hip/hip_runtime.h>
#include <hip/hip_bf16.h>

typedef __bf16 bf16x8 __attribute__((ext_vector_type(8)));
typedef __bf16 bf16x4 __attribute__((ext_vector_type(4)));
typedef float fx4 __attribute__((ext_vector_type(4)));
typedef float fx16 __attribute__((ext_vector_type(16)));

#define AS1 __attribute__((address_space(1)))
#define AS3 __attribute__((address_space(3)))

// ---------------------------------------------------------------- cast x -> bf16
__global__ __launch_bounds__(256) void cast_x(const float4* __restrict__ X, __bf16* __restrict__ Xb) {
    int i = blockIdx.x * 256 + threadIdx.x;
    float4 v = X[i];
    bf16x4 o = { (__bf16)v.x, (__bf16)v.y, (__bf16)v.z, (__bf16)v.w };
    *(bf16x4*)(Xb + (size_t)i * 4) = o;
}

// ------------------------------------------------- all 4 weight transposes in one launch
__global__ __launch_bounds__(256) void transpose_all(const float* __restrict__ wq, const float* __restrict__ wk,
                                                     const float* __restrict__ wv, const float* __restrict__ wo,
                                                     __bf16* __restrict__ WqkvT, __bf16* __restrict__ WoT) {
    constexpr int K = 2048;
    __shared__ float t[32][33];
    const int bx = blockIdx.x;
    const float* W; __bf16* Wt; int N, n0;
    if (bx < 64)      { W = wq; Wt = WqkvT;                        N = 2048; n0 = bx * 32; }
    else if (bx < 80) { W = wk; Wt = WqkvT + (size_t)2048 * 2048;  N = 512;  n0 = (bx - 64) * 32; }
    else if (bx < 96) { W = wv; Wt = WqkvT + (size_t)2560 * 2048;  N = 512;  n0 = (bx - 80) * 32; }
    else              { W = wo; Wt = WoT;                          N = 2048; n0 = (bx - 96) * 32; }
    const int tx = threadIdx.x & 31, ty = threadIdx.x >> 5;
    const int k0 = blockIdx.y * 32;
#pragma unroll
    for (int i = 0; i < 4; ++i)
        t[ty + i * 8][tx] = W[(size_t)(k0 + ty + i * 8) * N + n0 + tx];
    __syncthreads();
#pragma unroll
    for (int i = 0; i < 4; ++i)
        Wt[(size_t)(n0 + ty + i * 8) * K + k0 + tx] = (__bf16)t[tx][ty + i * 8];
}

// ------------------------------------------------- QKV GEMM, BN=64, BK=64, fused RoPE/split
__global__ __launch_bounds__(256) void gemm_qkv(const __bf16* __restrict__ A, const __bf16* __restrict__ Bt,
                                                __bf16* __restrict__ Qr, __bf16* __restrict__ Kr,
                                                __bf16* __restrict__ Vt) {
    constexpr int K = 2048;
    __shared__ __align__(16) __bf16 lA[2][128 * 32];
    __shared__ __align__(16) __bf16 lB[2][64 * 32];
    const int tid = threadIdx.x;
    const int wave = tid >> 6, lane = tid & 63;
    const int quad = lane >> 4, l16 = lane & 15;
    const int m0 = blockIdx.x * 128, n0 = blockIdx.y * 64;
    fx4 acc[2][4] = {};

    const __bf16* csrc[6]; __bf16* cdst[6];
#pragma unroll
    for (int it = 0; it < 6; ++it) {
        const int idx = wave * 6 + it;
        const int r4 = lane >> 2, c8 = (lane & 3) * 8;
        if (idx < 16) {
            const int kh = idx & 1, s = idx >> 1;
            csrc[it] = A + (size_t)(m0 + s * 16 + r4) * K + kh * 32 + c8;
            cdst[it] = &lA[kh][s * 512 + lane * 8];
        } else {
            const int b = idx - 16, kh = b & 1, s = b >> 1;
            csrc[it] = Bt + (size_t)(n0 + s * 16 + r4) * K + kh * 32 + c8;
            cdst[it] = &lB[kh][s * 512 + lane * 8];
        }
    }

    for (int k0 = 0; k0 < K; k0 += 64) {
        __syncthreads();
#pragma unroll
        for (int it = 0; it < 6; ++it)
            __builtin_amdgcn_global_load_lds((const AS1 void*)(csrc[it] + k0),
                                             (AS3 void*)cdst[it], 16, 0, 0);
        __builtin_amdgcn_s_waitcnt(0);
        __syncthreads();

#pragma unroll
        for (int kc = 0; kc < 2; ++kc) {
            bf16x8 af[2], bfr[4];
#pragma unroll
            for (int i = 0; i < 2; ++i) af[i] = *(const bf16x8*)&lA[kc][(wave * 32 + i * 16 + l16) * 32 + quad * 8];
#pragma unroll
            for (int j = 0; j < 4; ++j) bfr[j] = *(const bf16x8*)&lB[kc][(j * 16 + l16) * 32 + quad * 8];
#pragma unroll
            for (int i = 0; i < 2; ++i)
#pragma unroll
                for (int j = 0; j < 4; ++j)
                    acc[i][j] = __builtin_amdgcn_mfma_f32_16x16x32_bf16(af[i], bfr[j], acc[i][j], 0, 0, 0);
        }
    }

    const int by = blockIdx.y;
    if (by < 40) {
        const float scale = (by < 32) ? 0.18033688011112042f : 1.0f;   // Q: 0.125*log2(e)
        __bf16* base = (by < 32) ? (Qr + (size_t)by * 2048 * 64)
                                 : (Kr + (size_t)(by - 32) * 2048 * 64);
#pragma unroll
        for (int jj = 0; jj < 2; ++jj) {
            const int dlo = jj * 16 + l16;
            const float inv = __builtin_amdgcn_exp2f(-(float)dlo * 0.41524101186092029f);
#pragma unroll
            for (int i = 0; i < 2; ++i)
#pragma unroll
                for (int r = 0; r < 4; ++r) {
                    const int s = m0 + wave * 32 + i * 16 + quad * 4 + r;
                    float sn, cs;
                    __sincosf((float)s * inv, &sn, &cs);
                    const float lo = acc[i][jj][r], hv = acc[i][jj + 2][r];
                    base[(size_t)s * 64 + dlo]      = (__bf16)((lo * cs - hv * sn) * scale);
                    base[(size_t)s * 64 + dlo + 32] = (__bf16)((hv * cs + lo * sn) * scale);
                }
        }
    } else {
        __bf16* vb = Vt + (size_t)(by - 40) * 64 * 2048;
#pragma unroll
        for (int i = 0; i < 2; ++i)
#pragma unroll
            for (int j = 0; j < 4; ++j) {
                const int d = j * 16 + l16;
                const int s0 = m0 + wave * 32 + i * 16 + quad * 4;
                bf16x4 p;
#pragma unroll
                for (int r = 0; r < 4; ++r) p[r] = (__bf16)acc[i][j][r];
                *(bf16x4*)&vb[(size_t)d * 2048 + s0] = p;
            }
    }
}

// ------------------------------------------------- out-projection GEMM, split-K=2
__global__ __launch_bounds__(256) void gemm_bt_sk(const __bf16* __restrict__ A, const __bf16* __restrict__ Bt,
                                                  float* __restrict__ C0, float* __restrict__ C1,
                                                  int M, int N, int K) {
    __shared__ __align__(16) __bf16 lA[128 * 32];
    __shared__ __align__(16) __bf16 lB[128 * 32];
    const int tid = threadIdx.x;
    const int wave = tid >> 6, lane = tid & 63;
    const int quad = lane >> 4, l16 = lane & 15;
    const int m0 = blockIdx.x * 128, n0 = blockIdx.y * 128;
    const int kz = blockIdx.z;
    const int kbeg = kz * (K >> 1), kend = kbeg + (K >> 1);
    float* C = kz ? C1 : C0;
    const int wm = (wave >> 1) * 64, wn = (wave & 1) * 64;
    fx4 acc[4][4] = {};

    const int st0 = wave * 1024;
    const int st1 = 4096 + wave * 1024;
    const int r0 = (st0 + lane * 16) >> 6, c0 = ((st0 + lane * 16) & 63) >> 1;
    const int r1 = (st1 + lane * 16) >> 6, c1 = ((st1 + lane * 16) & 63) >> 1;

    for (int k0 = kbeg; k0 < kend; k0 += 32) {
        __syncthreads();
        __builtin_amdgcn_global_load_lds((const AS1 void*)(A + (size_t)(m0 + r0) * K + k0 + c0),
                                         (AS3 void*)(lA + (st0 >> 1)), 16, 0, 0);
        __builtin_amdgcn_global_load_lds((const AS1 void*)(A + (size_t)(m0 + r1) * K + k0 + c1),
                                         (AS3 void*)(lA + (st1 >> 1)), 16, 0, 0);
        __builtin_amdgcn_global_load_lds((const AS1 void*)(Bt + (size_t)(n0 + r0) * K + k0 + c0),
                                         (AS3 void*)(lB + (st0 >> 1)), 16, 0, 0);
        __builtin_amdgcn_global_load_lds((const AS1 void*)(Bt + (size_t)(n0 + r1) * K + k0 + c1),
                                         (AS3 void*)(lB + (st1 >> 1)), 16, 0, 0);
        __builtin_amdgcn_s_waitcnt(0);
        __syncthreads();

        bf16x8 af[4], bfr[4];
#pragma unroll
        for (int i = 0; i < 4; ++i) af[i] = *(const bf16x8*)&lA[(wm + i * 16 + l16) * 32 + quad * 8];
#pragma unroll
        for (int j = 0; j < 4; ++j) bfr[j] = *(const bf16x8*)&lB[(wn + j * 16 + l16) * 32 + quad * 8];
#pragma unroll
        for (int i = 0; i < 4; ++i)
#pragma unroll
            for (int j = 0; j < 4; ++j)
                acc[i][j] = __builtin_amdgcn_mfma_f32_16x16x32_bf16(af[i], bfr[j], acc[i][j], 0, 0, 0);
    }
#pragma unroll
    for (int i = 0; i < 4; ++i)
#pragma unroll
        for (int j = 0; j < 4; ++j) {
            const int row = m0 + wm + i * 16 + quad * 4;
            const int col = n0 + wn + j * 16 + l16;
#pragma unroll
            for (int r = 0; r < 4; ++r)
                C[(size_t)(row + r) * N + col] = acc[i][j][r];
        }
}

// ------------------------------------------------- out += partial (deterministic split-K reduce)
__global__ __launch_bounds__(256) void reduce_add(float4* __restrict__ out, const float4* __restrict__ p) {
    const int i = blockIdx.x * 256 + threadIdx.x;
    float4 a = out[i];
    const float4 b = p[i];
    a.x += b.x; a.y += b.y; a.z += b.z; a.w += b.w;
    out[i] = a;
}

// ------------------------------------------------- flash attention: BARRIER-FREE, 1 wave per block
// grid 2048 x 64thr: block = (q-tile of 32 rows, head). Each wave owns its whole
// softmax row-block and streams all 2048 keys in 32-key tiles -- every MFMA fragment
// is staged by the wave's own lanes, so NO __syncthreads exist. Same-wave LDS
// WAR/RAW ordering is guaranteed by in-order DS issue + compiler lgkmcnt.
// kvh = blockIdx.x & 7 swizzle: block id%8 round-robins over XCDs, pinning each
// kvh's 512 KB K/V working set into one XCD's 4 MB L2.
// Inner math identical to R6/R8 (S^T = K.Q^T, fixed-max exp2 softmax, permuted-V
// PV with B-operand packed straight from score regs), just 32-key tiles.
__global__ __launch_bounds__(64, 2) void flash_attn(const __bf16* __restrict__ Qr, const __bf16* __restrict__ Kr,
                                                    const __bf16* __restrict__ Vt, __bf16* __restrict__ O) {
    constexpr int S = 2048;
    __shared__ __align__(16) __bf16 lK[32 * 72];   // [key][d] stride 72
    __shared__ __align__(16) __bf16 lV[64 * 72];   // [d][slot] stride 72 (slots 0..31 used)
    const int id = blockIdx.x;
    const int kvh = id & 7;                        // XCD-aligned KV working set
    const int tq = id >> 3;                        // 0..255
    const int qtile = tq & 63;
    const int h = kvh * 4 + (tq >> 6);
    const int lane = threadIdx.x;
    const int l32 = lane & 31, hi = lane >> 5;

    const __bf16* qptr = Qr + ((size_t)h * S + qtile * 32 + l32) * 64;
    bf16x8 qf[4];
#pragma unroll
    for (int kc = 0; kc < 4; ++kc) qf[kc] = *(const bf16x8*)(qptr + kc * 16 + hi * 8);

    const __bf16* Kbase = Kr + (size_t)kvh * S * 64;
    const __bf16* Vbase = Vt + (size_t)kvh * 64 * S;

    // staging lane map: K -- 2 lanes per key-row (64B each, fully coalesced 4KB/instr);
    // V -- 4 lanes per d-row (64B each).
    const int kr = lane >> 1, kc2 = (lane & 1) * 32;
    const int vr = lane >> 2, vc = (lane & 3) * 8;
    const int vslot = (vc & 16) | ((vc & 8) >> 1);     // key bits2<->3 swap (chunk-of-16 local)

    bf16x8 kst[4], vst[4];
    // load tile 0 into regs
#pragma unroll
    for (int u = 0; u < 4; ++u) kst[u] = *(const bf16x8*)(Kbase + (size_t)kr * 64 + kc2 + u * 8);
#pragma unroll
    for (int p = 0; p < 4; ++p) vst[p] = *(const bf16x8*)(Vbase + (size_t)(vr + p * 16) * S + vc);

    // write tile 0 to LDS, then prefetch tile 1
#pragma unroll
    for (int u = 0; u < 4; ++u) *(bf16x8*)&lK[kr * 72 + kc2 + u * 8] = kst[u];
#pragma unroll
    for (int p = 0; p < 4; ++p) {
        bf16x4 lo = { vst[p][0], vst[p][1], vst[p][2], vst[p][3] };
        bf16x4 hi4 = { vst[p][4], vst[p][5], vst[p][6], vst[p][7] };
        *(bf16x4*)&lV[(vr + p * 16) * 72 + vslot]     = lo;
        *(bf16x4*)&lV[(vr + p * 16) * 72 + vslot + 8] = hi4;
    }
#pragma unroll
    for (int u = 0; u < 4; ++u) kst[u] = *(const bf16x8*)(Kbase + (size_t)(32 + kr) * 64 + kc2 + u * 8);
#pragma unroll
    for (int p = 0; p < 4; ++p) vst[p] = *(const bf16x8*)(Vbase + (size_t)(vr + p * 16) * S + 32 + vc);

    fx16 ov0, ov1;
#pragma unroll
    for (int i = 0; i < 16; ++i) { ov0[i] = 0.f; ov1[i] = 0.f; }
    float l_acc = 0.f;

    for (int it = 0; it < 64; ++it) {
        // S^T = K . Q^T over this 32-key tile (reads of tile it)
        fx16 sc;
#pragma unroll
        for (int i = 0; i < 16; ++i) sc[i] = 0.f;
#pragma unroll
        for (int kc = 0; kc < 4; ++kc) {
            const bf16x8 a = *(const bf16x8*)&lK[l32 * 72 + kc * 16 + hi * 8];
            sc = __builtin_amdgcn_mfma_f32_32x32x16_bf16(a, qf[kc], sc, 0, 0, 0);
        }

        // fixed-max softmax fused into PV (permuted-V: pb packed straight from sc)
#pragma unroll
        for (int c = 0; c < 2; ++c) {
            bf16x8 pb;
#pragma unroll
            for (int j = 0; j < 8; ++j) {
                const float p = __builtin_amdgcn_exp2f(sc[c * 8 + j]);
                l_acc += p;
                pb[j] = (__bf16)p;
            }
            const bf16x8 va0 = *(const bf16x8*)&lV[l32 * 72 + c * 16 + hi * 8];
            const bf16x8 va1 = *(const bf16x8*)&lV[(32 + l32) * 72 + c * 16 + hi * 8];
            ov0 = __builtin_amdgcn_mfma_f32_32x32x16_bf16(va0, pb, ov0, 0, 0, 0);
            ov1 = __builtin_amdgcn_mfma_f32_32x32x16_bf16(va1, pb, ov1, 0, 0, 0);
        }

        // stage tile it+1 (regs loaded last iter) AFTER this tile's reads; prefetch it+2
        if (it + 1 < 64) {
#pragma unroll
            for (int u = 0; u < 4; ++u) *(bf16x8*)&lK[kr * 72 + kc2 + u * 8] = kst[u];
#pragma unroll
            for (int p = 0; p < 4; ++p) {
                bf16x4 lo = { vst[p][0], vst[p][1], vst[p][2], vst[p][3] };
                bf16x4 hi4 = { vst[p][4], vst[p][5], vst[p][6], vst[p][7] };
                *(bf16x4*)&lV[(vr + p * 16) * 72 + vslot]     = lo;
                *(bf16x4*)&lV[(vr + p * 16) * 72 + vslot + 8] = hi4;
            }
            const int ktn = (it + 2 < 64) ? it + 2 : 63;
#pragma unroll
            for (int u = 0; u < 4; ++u)
                kst[u] = *(const bf16x8*)(Kbase + (size_t)(ktn * 32 + kr) * 64 + kc2 + u * 8);
#pragma unroll
            for (int p = 0; p < 4; ++p)
                vst[p] = *(const bf16x8*)(Vbase + (size_t)(vr + p * 16) * S + ktn * 32 + vc);
        }
    }

    // l: lane holds 16 keys/tile of q=l32; partner lane^32 holds the complement
    const float l_tot = l_acc + __shfl_xor(l_acc, 32, 64);
    const float inv_l = 1.0f / l_tot;

    // epilogue: O[qrow][h*64 + d], d = dt*32 + rg2*8 + hi*4 + r
    const int qrow = qtile * 32 + l32;
#pragma unroll
    for (int dt = 0; dt < 2; ++dt)
#pragma unroll
        for (int rg2 = 0; rg2 < 4; ++rg2) {
            bf16x4 o4;
#pragma unroll
            for (int r = 0; r < 4; ++r)
                o4[r] = (__bf16)((dt ? ov1[rg2 * 4 + r] : ov0[rg2 * 4 + r]) * inv_l);
            const int col = h * 64 + dt * 32 + rg2 * 8 + hi * 4;
            *(bf16x4*)(O + (size_t)qrow * 2048 + col) = o4;
        }
}

// ----------------------------------------------------------------------------
extern "C" void kernel_launch(void* const* d_in, const int* in_sizes, int n_in,
                              void* d_out, int out_size, void* d_ws, size_t ws_size,
                              hipStream_t stream) {
    const float* x  = (const float*)d_in[0];
    const float* wq = (const float*)d_in[1];
    const float* wk = (const float*)d_in[2];
    const float* wv = (const float*)d_in[3];
    const float* wo = (const float*)d_in[4];
    float* out = (float*)d_out;
    char* ws = (char*)d_ws;

    __bf16* Xb    = (__bf16*)ws;                        // [0, 8M)
    __bf16* WqkvT = (__bf16*)(ws + ((size_t)8 << 20));  // [8M, 20M)  3072 x 2048
    __bf16* WoT   = (__bf16*)(ws + ((size_t)20 << 20)); // [20M, 28M) 2048 x 2048
    __bf16* Qr    = (__bf16*)(ws + ((size_t)28 << 20)); // [28M, 36M) 32 x 2048 x 64
    __bf16* Kr    = (__bf16*)(ws + ((size_t)36 << 20)); // [36M, 38M)  8 x 2048 x 64
    __bf16* Vt    = (__bf16*)(ws + ((size_t)38 << 20)); // [38M, 40M)  8 x 64 x 2048
    __bf16* Ob    = (__bf16*)(ws + ((size_t)40 << 20)); // [40M, 48M) 2048 x 2048
    float*  Cp    = (float*)ws;                         // [0, 16.8M) split-K partial (Xb/WqkvT dead)

    cast_x<<<4096, 256, 0, stream>>>((const float4*)x, Xb);
    transpose_all<<<dim3(160, 64), 256, 0, stream>>>(wq, wk, wv, wo, WqkvT, WoT);

    gemm_qkv<<<dim3(16, 48), 256, 0, stream>>>(Xb, WqkvT, Qr, Kr, Vt);
    flash_attn<<<2048, 64, 0, stream>>>(Qr, Kr, Vt, Ob);
    gemm_bt_sk<<<dim3(16, 16, 2), 256, 0, stream>>>(Ob, WoT, out, Cp, 2048, 2048, 2048);
    reduce_add<<<4096, 256, 0, stream>>>((float4*)out, (const float4*)Cp);
}

// Round 11
// 237.379 us; speedup vs baseline: 1.0335x; 1.0335x over previous
//
#include <hip/hip_runtime.h>
#include <hip/hip_bf16.h>

typedef __bf16 bf16x8 __attribute__((ext_vector_type(8)));
typedef __bf16 bf16x4 __attribute__((ext_vector_type(4)));
typedef float fx4 __attribute__((ext_vector_type(4)));
typedef float fx16 __attribute__((ext_vector_type(16)));

#define AS1 __attribute__((address_space(1)))
#define AS3 __attribute__((address_space(3)))

// ------------------------------------------------- prep: cast x->bf16 + all 4 weight transposes
// blocks [0,4096): cast; [4096, 14336): transpose (tbx = r%160 selects matrix/col-tile, tby = r/160 k-tile)
__global__ __launch_bounds__(256) void prep(const float4* __restrict__ X, __bf16* __restrict__ Xb,
                                            const float* __restrict__ wq, const float* __restrict__ wk,
                                            const float* __restrict__ wv, const float* __restrict__ wo,
                                            __bf16* __restrict__ WqkvT, __bf16* __restrict__ WoT) {
    constexpr int K = 2048;
    __shared__ float t[32][33];
    const int bx = blockIdx.x;
    if (bx < 4096) {
        const int i = bx * 256 + threadIdx.x;
        float4 v = X[i];
        bf16x4 o = { (__bf16)v.x, (__bf16)v.y, (__bf16)v.z, (__bf16)v.w };
        *(bf16x4*)(Xb + (size_t)i * 4) = o;
        return;
    }
    const int r = bx - 4096;
    const int tbx = r % 160, tby = r / 160;
    const float* W; __bf16* Wt; int N, n0;
    if (tbx < 64)      { W = wq; Wt = WqkvT;                        N = 2048; n0 = tbx * 32; }
    else if (tbx < 80) { W = wk; Wt = WqkvT + (size_t)2048 * 2048;  N = 512;  n0 = (tbx - 64) * 32; }
    else if (tbx < 96) { W = wv; Wt = WqkvT + (size_t)2560 * 2048;  N = 512;  n0 = (tbx - 80) * 32; }
    else               { W = wo; Wt = WoT;                          N = 2048; n0 = (tbx - 96) * 32; }
    const int tx = threadIdx.x & 31, ty = threadIdx.x >> 5;
    const int k0 = tby * 32;
#pragma unroll
    for (int i = 0; i < 4; ++i)
        t[ty + i * 8][tx] = W[(size_t)(k0 + ty + i * 8) * N + n0 + tx];
    __syncthreads();
#pragma unroll
    for (int i = 0; i < 4; ++i)
        Wt[(size_t)(n0 + ty + i * 8) * K + k0 + tx] = (__bf16)t[tx][ty + i * 8];
}

// ------------------------------------------------- QKV GEMM, BN=64, BK=64, fused RoPE/split
__global__ __launch_bounds__(256) void gemm_qkv(const __bf16* __restrict__ A, const __bf16* __restrict__ Bt,
                                                __bf16* __restrict__ Qr, __bf16* __restrict__ Kr,
                                                __bf16* __restrict__ Vt) {
    constexpr int K = 2048;
    __shared__ __align__(16) __bf16 lA[2][128 * 32];
    __shared__ __align__(16) __bf16 lB[2][64 * 32];
    const int tid = threadIdx.x;
    const int wave = tid >> 6, lane = tid & 63;
    const int quad = lane >> 4, l16 = lane & 15;
    const int m0 = blockIdx.x * 128, n0 = blockIdx.y * 64;
    fx4 acc[2][4] = {};

    const __bf16* csrc[6]; __bf16* cdst[6];
#pragma unroll
    for (int it = 0; it < 6; ++it) {
        const int idx = wave * 6 + it;
        const int r4 = lane >> 2, c8 = (lane & 3) * 8;
        if (idx < 16) {
            const int kh = idx & 1, s = idx >> 1;
            csrc[it] = A + (size_t)(m0 + s * 16 + r4) * K + kh * 32 + c8;
            cdst[it] = &lA[kh][s * 512 + lane * 8];
        } else {
            const int b = idx - 16, kh = b & 1, s = b >> 1;
            csrc[it] = Bt + (size_t)(n0 + s * 16 + r4) * K + kh * 32 + c8;
            cdst[it] = &lB[kh][s * 512 + lane * 8];
        }
    }

    for (int k0 = 0; k0 < K; k0 += 64) {
        __syncthreads();
#pragma unroll
        for (int it = 0; it < 6; ++it)
            __builtin_amdgcn_global_load_lds((const AS1 void*)(csrc[it] + k0),
                                             (AS3 void*)cdst[it], 16, 0, 0);
        __builtin_amdgcn_s_waitcnt(0);
        __syncthreads();

#pragma unroll
        for (int kc = 0; kc < 2; ++kc) {
            bf16x8 af[2], bfr[4];
#pragma unroll
            for (int i = 0; i < 2; ++i) af[i] = *(const bf16x8*)&lA[kc][(wave * 32 + i * 16 + l16) * 32 + quad * 8];
#pragma unroll
            for (int j = 0; j < 4; ++j) bfr[j] = *(const bf16x8*)&lB[kc][(j * 16 + l16) * 32 + quad * 8];
#pragma unroll
            for (int i = 0; i < 2; ++i)
#pragma unroll
                for (int j = 0; j < 4; ++j)
                    acc[i][j] = __builtin_amdgcn_mfma_f32_16x16x32_bf16(af[i], bfr[j], acc[i][j], 0, 0, 0);
        }
    }

    const int by = blockIdx.y;
    if (by < 40) {
        const float scale = (by < 32) ? 0.18033688011112042f : 1.0f;   // Q: 0.125*log2(e)
        __bf16* base = (by < 32) ? (Qr + (size_t)by * 2048 * 64)
                                 : (Kr + (size_t)(by - 32) * 2048 * 64);
#pragma unroll
        for (int jj = 0; jj < 2; ++jj) {
            const int dlo = jj * 16 + l16;
            const float inv = __builtin_amdgcn_exp2f(-(float)dlo * 0.41524101186092029f);
#pragma unroll
            for (int i = 0; i < 2; ++i)
#pragma unroll
                for (int r = 0; r < 4; ++r) {
                    const int s = m0 + wave * 32 + i * 16 + quad * 4 + r;
                    float sn, cs;
                    __sincosf((float)s * inv, &sn, &cs);
                    const float lo = acc[i][jj][r], hv = acc[i][jj + 2][r];
                    base[(size_t)s * 64 + dlo]      = (__bf16)((lo * cs - hv * sn) * scale);
                    base[(size_t)s * 64 + dlo + 32] = (__bf16)((hv * cs + lo * sn) * scale);
                }
        }
    } else {
        __bf16* vb = Vt + (size_t)(by - 40) * 64 * 2048;
#pragma unroll
        for (int i = 0; i < 2; ++i)
#pragma unroll
            for (int j = 0; j < 4; ++j) {
                const int d = j * 16 + l16;
                const int s0 = m0 + wave * 32 + i * 16 + quad * 4;
                bf16x4 p;
#pragma unroll
                for (int r = 0; r < 4; ++r) p[r] = (__bf16)acc[i][j][r];
                *(bf16x4*)&vb[(size_t)d * 2048 + s0] = p;
            }
    }
}

// ------------------------------------------------- out-projection GEMM, split-K=2, atomic fp32 epilogue
// d_out is zeroed by hipMemsetAsync before this launch; both kz halves atomicAdd.
// Exactly 2 commuting adds per element onto 0.0 -> order-invariant (a+b == b+a), deterministic.
__global__ __launch_bounds__(256) void gemm_bt_at(const __bf16* __restrict__ A, const __bf16* __restrict__ Bt,
                                                  float* __restrict__ C, int M, int N, int K) {
    __shared__ __align__(16) __bf16 lA[128 * 32];
    __shared__ __align__(16) __bf16 lB[128 * 32];
    const int tid = threadIdx.x;
    const int wave = tid >> 6, lane = tid & 63;
    const int quad = lane >> 4, l16 = lane & 15;
    const int m0 = blockIdx.x * 128, n0 = blockIdx.y * 128;
    const int kz = blockIdx.z;
    const int kbeg = kz * (K >> 1), kend = kbeg + (K >> 1);
    const int wm = (wave >> 1) * 64, wn = (wave & 1) * 64;
    fx4 acc[4][4] = {};

    const int st0 = wave * 1024;
    const int st1 = 4096 + wave * 1024;
    const int r0 = (st0 + lane * 16) >> 6, c0 = ((st0 + lane * 16) & 63) >> 1;
    const int r1 = (st1 + lane * 16) >> 6, c1 = ((st1 + lane * 16) & 63) >> 1;

    for (int k0 = kbeg; k0 < kend; k0 += 32) {
        __syncthreads();
        __builtin_amdgcn_global_load_lds((const AS1 void*)(A + (size_t)(m0 + r0) * K + k0 + c0),
                                         (AS3 void*)(lA + (st0 >> 1)), 16, 0, 0);
        __builtin_amdgcn_global_load_lds((const AS1 void*)(A + (size_t)(m0 + r1) * K + k0 + c1),
                                         (AS3 void*)(lA + (st1 >> 1)), 16, 0, 0);
        __builtin_amdgcn_global_load_lds((const AS1 void*)(Bt + (size_t)(n0 + r0) * K + k0 + c0),
                                         (AS3 void*)(lB + (st0 >> 1)), 16, 0, 0);
        __builtin_amdgcn_global_load_lds((const AS1 void*)(Bt + (size_t)(n0 + r1) * K + k0 + c1),
                                         (AS3 void*)(lB + (st1 >> 1)), 16, 0, 0);
        __builtin_amdgcn_s_waitcnt(0);
        __syncthreads();

        bf16x8 af[4], bfr[4];
#pragma unroll
        for (int i = 0; i < 4; ++i) af[i] = *(const bf16x8*)&lA[(wm + i * 16 + l16) * 32 + quad * 8];
#pragma unroll
        for (int j = 0; j < 4; ++j) bfr[j] = *(const bf16x8*)&lB[(wn + j * 16 + l16) * 32 + quad * 8];
#pragma unroll
        for (int i = 0; i < 4; ++i)
#pragma unroll
            for (int j = 0; j < 4; ++j)
                acc[i][j] = __builtin_amdgcn_mfma_f32_16x16x32_bf16(af[i], bfr[j], acc[i][j], 0, 0, 0);
    }
#pragma unroll
    for (int i = 0; i < 4; ++i)
#pragma unroll
        for (int j = 0; j < 4; ++j) {
            const int row = m0 + wm + i * 16 + quad * 4;
            const int col = n0 + wn + j * 16 + l16;
#pragma unroll
            for (int r = 0; r < 4; ++r)
                atomicAdd(&C[(size_t)(row + r) * N + col], acc[i][j][r]);
        }
}

// ------------------------------------------------- flash attention: no-P-LDS + 8-wave split-K + LDS dbuf
// (R8 version, verified 44.9 us.) grid (16 q-tiles of 128, 32 heads), 512 thr = 8 waves.
// Waves 0-3 even key-tiles, 4-7 odd, private K/V buffers per group, double-buffered:
// one barrier per iteration. PV B-operand packed straight from exp2'd score regs
// (permuted-V). Fixed-max softmax -> cross-group combine via adds through LDS.
__global__ __launch_bounds__(512, 4) void flash_attn(const __bf16* __restrict__ Qr, const __bf16* __restrict__ Kr,
                                                     const __bf16* __restrict__ Vt, __bf16* __restrict__ O) {
    constexpr int S = 2048;
    __shared__ __align__(16) __bf16 smem[2][4 * 64 * 72];   // 73728 B, 2 buffers
    const int qt = blockIdx.x, h = blockIdx.y, kvh = h >> 2;
    const int tid = threadIdx.x, wave = tid >> 6, lane = tid & 63;
    const int grp = wave >> 2, w4 = wave & 3;
    const int l32 = lane & 31, hi = lane >> 5;
    const int goff = grp * 2 * 4608;

    const int qrow = qt * 128 + w4 * 32 + l32;
    const __bf16* qptr = Qr + ((size_t)h * S + qrow) * 64;
    bf16x8 qf[4];
#pragma unroll
    for (int kc = 0; kc < 4; ++kc) qf[kc] = *(const bf16x8*)(qptr + kc * 16 + hi * 8);

    const __bf16* Kbase = Kr + (size_t)kvh * S * 64;
    const __bf16* Vbase = Vt + (size_t)kvh * 64 * S;

    const int gtid = tid & 255;
    const int krow = gtid >> 3;                 // 0..31
    const int kcol = (gtid & 7) * 8;
    const int vslot = (kcol & 48) | ((kcol & 8) >> 1);   // permuted dest of keys [kcol, kcol+4)

    bf16x8 kreg0 = *(const bf16x8*)(Kbase + (size_t)(grp * 64 + krow) * 64 + kcol);
    bf16x8 kreg1 = *(const bf16x8*)(Kbase + (size_t)(grp * 64 + 32 + krow) * 64 + kcol);
    bf16x8 vreg0 = *(const bf16x8*)(Vbase + (size_t)krow * S + grp * 64 + kcol);
    bf16x8 vreg1 = *(const bf16x8*)(Vbase + (size_t)(32 + krow) * S + grp * 64 + kcol);

    fx16 ov0, ov1;
#pragma unroll
    for (int i = 0; i < 16; ++i) { ov0[i] = 0.f; ov1[i] = 0.f; }
    float l_acc = 0.f;

    {
        __bf16* nK = &smem[0][goff];
        __bf16* nV = nK + 4608;
        *(bf16x8*)&nK[krow * 72 + kcol] = kreg0;
        *(bf16x8*)&nK[(32 + krow) * 72 + kcol] = kreg1;
        bf16x4 v0lo = { vreg0[0], vreg0[1], vreg0[2], vreg0[3] };
        bf16x4 v0hi = { vreg0[4], vreg0[5], vreg0[6], vreg0[7] };
        bf16x4 v1lo = { vreg1[0], vreg1[1], vreg1[2], vreg1[3] };
        bf16x4 v1hi = { vreg1[4], vreg1[5], vreg1[6], vreg1[7] };
        *(bf16x4*)&nV[krow * 72 + vslot]            = v0lo;
        *(bf16x4*)&nV[krow * 72 + vslot + 8]        = v0hi;
        *(bf16x4*)&nV[(32 + krow) * 72 + vslot]     = v1lo;
        *(bf16x4*)&nV[(32 + krow) * 72 + vslot + 8] = v1hi;
        const int kt1 = 2 + grp;
        kreg0 = *(const bf16x8*)(Kbase + (size_t)(kt1 * 64 + krow) * 64 + kcol);
        kreg1 = *(const bf16x8*)(Kbase + (size_t)(kt1 * 64 + 32 + krow) * 64 + kcol);
        vreg0 = *(const bf16x8*)(Vbase + (size_t)krow * S + kt1 * 64 + kcol);
        vreg1 = *(const bf16x8*)(Vbase + (size_t)(32 + krow) * S + kt1 * 64 + kcol);
    }
    __syncthreads();

    for (int it = 0; it < 16; ++it) {
        __bf16* lKg = &smem[it & 1][goff];
        __bf16* lVg = lKg + 4608;

        if (it + 1 < 16) {
            __bf16* nK = &smem[(it + 1) & 1][goff];
            __bf16* nV = nK + 4608;
            *(bf16x8*)&nK[krow * 72 + kcol] = kreg0;
            *(bf16x8*)&nK[(32 + krow) * 72 + kcol] = kreg1;
            bf16x4 v0lo = { vreg0[0], vreg0[1], vreg0[2], vreg0[3] };
            bf16x4 v0hi = { vreg0[4], vreg0[5], vreg0[6], vreg0[7] };
            bf16x4 v1lo = { vreg1[0], vreg1[1], vreg1[2], vreg1[3] };
            bf16x4 v1hi = { vreg1[4], vreg1[5], vreg1[6], vreg1[7] };
            *(bf16x4*)&nV[krow * 72 + vslot]            = v0lo;
            *(bf16x4*)&nV[krow * 72 + vslot + 8]        = v0hi;
            *(bf16x4*)&nV[(32 + krow) * 72 + vslot]     = v1lo;
            *(bf16x4*)&nV[(32 + krow) * 72 + vslot + 8] = v1hi;
            const int it2 = (it + 2 < 16) ? it + 2 : 15;
            const int ktn = it2 * 2 + grp;
            kreg0 = *(const bf16x8*)(Kbase + (size_t)(ktn * 64 + krow) * 64 + kcol);
            kreg1 = *(const bf16x8*)(Kbase + (size_t)(ktn * 64 + 32 + krow) * 64 + kcol);
            vreg0 = *(const bf16x8*)(Vbase + (size_t)krow * S + ktn * 64 + kcol);
            vreg1 = *(const bf16x8*)(Vbase + (size_t)(32 + krow) * S + ktn * 64 + kcol);
        }

        fx16 sc0, sc1;
#pragma unroll
        for (int i = 0; i < 16; ++i) { sc0[i] = 0.f; sc1[i] = 0.f; }
#pragma unroll
        for (int kc = 0; kc < 4; ++kc) {
            const bf16x8 a0 = *(const bf16x8*)&lKg[l32 * 72 + kc * 16 + hi * 8];
            const bf16x8 a1 = *(const bf16x8*)&lKg[(32 + l32) * 72 + kc * 16 + hi * 8];
            sc0 = __builtin_amdgcn_mfma_f32_32x32x16_bf16(a0, qf[kc], sc0, 0, 0, 0);
            sc1 = __builtin_amdgcn_mfma_f32_32x32x16_bf16(a1, qf[kc], sc1, 0, 0, 0);
        }

#pragma unroll
        for (int h2 = 0; h2 < 2; ++h2) {
#pragma unroll
            for (int c = 0; c < 2; ++c) {
                bf16x8 pb;
#pragma unroll
                for (int j = 0; j < 8; ++j) {
                    const float sv = h2 ? sc1[c * 8 + j] : sc0[c * 8 + j];
                    const float p = __builtin_amdgcn_exp2f(sv);
                    l_acc += p;
                    pb[j] = (__bf16)p;
                }
                const int kcv = h2 * 2 + c;
                const bf16x8 va0 = *(const bf16x8*)&lVg[l32 * 72 + kcv * 16 + hi * 8];
                const bf16x8 va1 = *(const bf16x8*)&lVg[(32 + l32) * 72 + kcv * 16 + hi * 8];
                ov0 = __builtin_amdgcn_mfma_f32_32x32x16_bf16(va0, pb, ov0, 0, 0, 0);
                ov1 = __builtin_amdgcn_mfma_f32_32x32x16_bf16(va1, pb, ov1, 0, 0, 0);
            }
        }
        __syncthreads();
    }

    const float l_pair = l_acc + __shfl_xor(l_acc, 32, 64);

    fx4* lO = (fx4*)&smem[0][0];
    float* lL = (float*)(&smem[0][0] + 16384);   // byte 32768
    if (grp == 1) {
#pragma unroll
        for (int ic = 0; ic < 4; ++ic) {
            fx4 c0, c1;
#pragma unroll
            for (int r = 0; r < 4; ++r) { c0[r] = ov0[ic * 4 + r]; c1[r] = ov1[ic * 4 + r]; }
            lO[(ic * 4 + w4) * 64 + lane] = c0;
            lO[((ic + 4) * 4 + w4) * 64 + lane] = c1;
        }
        if (hi == 0) lL[w4 * 32 + l32] = l_pair;
    }
    __syncthreads();
    if (grp == 0) {
#pragma unroll
        for (int ic = 0; ic < 4; ++ic) {
            const fx4 c0 = lO[(ic * 4 + w4) * 64 + lane];
            const fx4 c1 = lO[((ic + 4) * 4 + w4) * 64 + lane];
#pragma unroll
            for (int r = 0; r < 4; ++r) { ov0[ic * 4 + r] += c0[r]; ov1[ic * 4 + r] += c1[r]; }
        }
        const float inv_l = 1.0f / (l_pair + lL[w4 * 32 + l32]);
#pragma unroll
        for (int dt = 0; dt < 2; ++dt)
#pragma unroll
            for (int rg2 = 0; rg2 < 4; ++rg2) {
                bf16x4 o4;
#pragma unroll
                for (int r = 0; r < 4; ++r)
                    o4[r] = (__bf16)((dt ? ov1[rg2 * 4 + r] : ov0[rg2 * 4 + r]) * inv_l);
                const int col = h * 64 + dt * 32 + rg2 * 8 + hi * 4;
                *(bf16x4*)(O + (size_t)qrow * 2048 + col) = o4;
            }
    }
}

// ----------------------------------------------------------------------------
extern "C" void kernel_launch(void* const* d_in, const int* in_sizes, int n_in,
                              void* d_out, int out_size, void* d_ws, size_t ws_size,
                              hipStream_t stream) {
    const float* x  = (const float*)d_in[0];
    const float* wq = (const float*)d_in[1];
    const float* wk = (const float*)d_in[2];
    const float* wv = (const float*)d_in[3];
    const float* wo = (const float*)d_in[4];
    float* out = (float*)d_out;
    char* ws = (char*)d_ws;

    __bf16* Xb    = (__bf16*)ws;                        // [0, 8M)
    __bf16* WqkvT = (__bf16*)(ws + ((size_t)8 << 20));  // [8M, 20M)  3072 x 2048
    __bf16* WoT   = (__bf16*)(ws + ((size_t)20 << 20)); // [20M, 28M) 2048 x 2048
    __bf16* Qr    = (__bf16*)(ws + ((size_t)28 << 20)); // [28M, 36M) 32 x 2048 x 64
    __bf16* Kr    = (__bf16*)(ws + ((size_t)36 << 20)); // [36M, 38M)  8 x 2048 x 64
    __bf16* Vt    = (__bf16*)(ws + ((size_t)38 << 20)); // [38M, 40M)  8 x 64 x 2048
    __bf16* Ob    = (__bf16*)(ws + ((size_t)40 << 20)); // [40M, 48M) 2048 x 2048

    hipMemsetAsync(out, 0, (size_t)2048 * 2048 * 4, stream);   // atomic-add target
    prep<<<14336, 256, 0, stream>>>((const float4*)x, Xb, wq, wk, wv, wo, WqkvT, WoT);
    gemm_qkv<<<dim3(16, 48), 256, 0, stream>>>(Xb, WqkvT, Qr, Kr, Vt);
    flash_attn<<<dim3(16, 32), 512, 0, stream>>>(Qr, Kr, Vt, Ob);
    gemm_bt_at<<<dim3(16, 16, 2), 256, 0, stream>>>(Ob, WoT, out, 2048, 2048, 2048);
}

// Round 12
// 231.103 us; speedup vs baseline: 1.0616x; 1.0272x over previous
//
#include <hip/hip_runtime.h>
#include <hip/hip_bf16.h>

typedef __bf16 bf16x8 __attribute__((ext_vector_type(8)));
typedef __bf16 bf16x4 __attribute__((ext_vector_type(4)));
typedef float fx4 __attribute__((ext_vector_type(4)));
typedef float fx16 __attribute__((ext_vector_type(16)));

#define AS1 __attribute__((address_space(1)))
#define AS3 __attribute__((address_space(3)))

// ------------------------------------------------- prep: cast x->bf16 + all 4 weight transposes
__global__ __launch_bounds__(256) void prep(const float4* __restrict__ X, __bf16* __restrict__ Xb,
                                            const float* __restrict__ wq, const float* __restrict__ wk,
                                            const float* __restrict__ wv, const float* __restrict__ wo,
                                            __bf16* __restrict__ WqkvT, __bf16* __restrict__ WoT) {
    constexpr int K = 2048;
    __shared__ float t[32][33];
    const int bx = blockIdx.x;
    if (bx < 4096) {
        const int i = bx * 256 + threadIdx.x;
        float4 v = X[i];
        bf16x4 o = { (__bf16)v.x, (__bf16)v.y, (__bf16)v.z, (__bf16)v.w };
        *(bf16x4*)(Xb + (size_t)i * 4) = o;
        return;
    }
    const int r = bx - 4096;
    const int tbx = r % 160, tby = r / 160;
    const float* W; __bf16* Wt; int N, n0;
    if (tbx < 64)      { W = wq; Wt = WqkvT;                        N = 2048; n0 = tbx * 32; }
    else if (tbx < 80) { W = wk; Wt = WqkvT + (size_t)2048 * 2048;  N = 512;  n0 = (tbx - 64) * 32; }
    else if (tbx < 96) { W = wv; Wt = WqkvT + (size_t)2560 * 2048;  N = 512;  n0 = (tbx - 80) * 32; }
    else               { W = wo; Wt = WoT;                          N = 2048; n0 = (tbx - 96) * 32; }
    const int tx = threadIdx.x & 31, ty = threadIdx.x >> 5;
    const int k0 = tby * 32;
#pragma unroll
    for (int i = 0; i < 4; ++i)
        t[ty + i * 8][tx] = W[(size_t)(k0 + ty + i * 8) * N + n0 + tx];
    __syncthreads();
#pragma unroll
    for (int i = 0; i < 4; ++i)
        Wt[(size_t)(n0 + ty + i * 8) * K + k0 + tx] = (__bf16)t[tx][ty + i * 8];
}

// ------------------------------------------------- QKV GEMM, BM=64, BN=64, BK=64, fused RoPE/split
// grid (32, 48) = 1536 blocks = 6 blocks/CU (LDS 16 KB). Wave owns 16 rows x 64 cols.
__global__ __launch_bounds__(256) void gemm_qkv(const __bf16* __restrict__ A, const __bf16* __restrict__ Bt,
                                                __bf16* __restrict__ Qr, __bf16* __restrict__ Kr,
                                                __bf16* __restrict__ Vt) {
    constexpr int K = 2048;
    __shared__ __align__(16) __bf16 lA[2][64 * 32];   // split k-halves
    __shared__ __align__(16) __bf16 lB[2][64 * 32];
    const int tid = threadIdx.x;
    const int wave = tid >> 6, lane = tid & 63;
    const int quad = lane >> 4, l16 = lane & 15;
    const int m0 = blockIdx.x * 64, n0 = blockIdx.y * 64;
    fx4 acc[4] = {};

    // 16 chunks of 1KB (A: 0..7, B: 8..15); 4 per wave. chunk: kh=idx&1, s=idx>>1,
    // rows s*16+(lane>>2), col kh*32+(lane&3)*8; dst = lX[kh] + s*512 + lane*8.
    const __bf16* csrc[4]; __bf16* cdst[4];
#pragma unroll
    for (int it = 0; it < 4; ++it) {
        const int idx = wave * 4 + it;
        const int r4 = lane >> 2, c8 = (lane & 3) * 8;
        if (idx < 8) {
            const int kh = idx & 1, s = idx >> 1;
            csrc[it] = A + (size_t)(m0 + s * 16 + r4) * K + kh * 32 + c8;
            cdst[it] = &lA[kh][s * 512 + lane * 8];
        } else {
            const int b = idx - 8, kh = b & 1, s = b >> 1;
            csrc[it] = Bt + (size_t)(n0 + s * 16 + r4) * K + kh * 32 + c8;
            cdst[it] = &lB[kh][s * 512 + lane * 8];
        }
    }

    for (int k0 = 0; k0 < K; k0 += 64) {
        __syncthreads();
#pragma unroll
        for (int it = 0; it < 4; ++it)
            __builtin_amdgcn_global_load_lds((const AS1 void*)(csrc[it] + k0),
                                             (AS3 void*)cdst[it], 16, 0, 0);
        __builtin_amdgcn_s_waitcnt(0);
        __syncthreads();

#pragma unroll
        for (int kc = 0; kc < 2; ++kc) {
            const bf16x8 af = *(const bf16x8*)&lA[kc][(wave * 16 + l16) * 32 + quad * 8];
            bf16x8 bfr[4];
#pragma unroll
            for (int j = 0; j < 4; ++j) bfr[j] = *(const bf16x8*)&lB[kc][(j * 16 + l16) * 32 + quad * 8];
#pragma unroll
            for (int j = 0; j < 4; ++j)
                acc[j] = __builtin_amdgcn_mfma_f32_16x16x32_bf16(af, bfr[j], acc[j], 0, 0, 0);
        }
    }

    // fused epilogue: d = j*16 + l16, s = m0 + wave*16 + quad*4 + r
    const int by = blockIdx.y;
    if (by < 40) {
        const float scale = (by < 32) ? 0.18033688011112042f : 1.0f;   // Q: 0.125*log2(e)
        __bf16* base = (by < 32) ? (Qr + (size_t)by * 2048 * 64)
                                 : (Kr + (size_t)(by - 32) * 2048 * 64);
#pragma unroll
        for (int jj = 0; jj < 2; ++jj) {
            const int dlo = jj * 16 + l16;
            const float inv = __builtin_amdgcn_exp2f(-(float)dlo * 0.41524101186092029f);
#pragma unroll
            for (int r = 0; r < 4; ++r) {
                const int s = m0 + wave * 16 + quad * 4 + r;
                float sn, cs;
                __sincosf((float)s * inv, &sn, &cs);
                const float lo = acc[jj][r], hv = acc[jj + 2][r];
                base[(size_t)s * 64 + dlo]      = (__bf16)((lo * cs - hv * sn) * scale);
                base[(size_t)s * 64 + dlo + 32] = (__bf16)((hv * cs + lo * sn) * scale);
            }
        }
    } else {
        __bf16* vb = Vt + (size_t)(by - 40) * 64 * 2048;
#pragma unroll
        for (int j = 0; j < 4; ++j) {
            const int d = j * 16 + l16;
            const int s0 = m0 + wave * 16 + quad * 4;
            bf16x4 p;
#pragma unroll
            for (int r = 0; r < 4; ++r) p[r] = (__bf16)acc[j][r];
            *(bf16x4*)&vb[(size_t)d * 2048 + s0] = p;
        }
    }
}

// ------------------------------------------------- out-projection GEMM, BM=64, BN=128, split-K=2
// grid (32, 16, 2) = 1024 blocks = 4 blocks/CU (LDS 12 KB). Waves 2x2, wave tile 32x64.
__global__ __launch_bounds__(256) void gemm_bt_sk(const __bf16* __restrict__ A, const __bf16* __restrict__ Bt,
                                                  float* __restrict__ C0, float* __restrict__ C1,
                                                  int M, int N, int K) {
    __shared__ __align__(16) __bf16 lA[64 * 32];
    __shared__ __align__(16) __bf16 lB[128 * 32];
    const int tid = threadIdx.x;
    const int wave = tid >> 6, lane = tid & 63;
    const int quad = lane >> 4, l16 = lane & 15;
    const int m0 = blockIdx.x * 64, n0 = blockIdx.y * 128;
    const int kz = blockIdx.z;
    const int kbeg = kz * (K >> 1), kend = kbeg + (K >> 1);
    float* C = kz ? C1 : C0;
    const int wm = (wave >> 1) * 32, wn = (wave & 1) * 64;
    fx4 acc[2][4] = {};

    // 12 chunks of 1KB (A: 0..3, B: 4..11); 3 per wave
    const __bf16* csrc[3]; __bf16* cdst[3];
#pragma unroll
    for (int it = 0; it < 3; ++it) {
        const int idx = wave * 3 + it;
        if (idx < 4) {
            const int boff = idx * 1024 + lane * 16;
            csrc[it] = A + (size_t)(m0 + (boff >> 6)) * K + ((boff & 63) >> 1);
            cdst[it] = lA + (boff >> 1);
        } else {
            const int boff = (idx - 4) * 1024 + lane * 16;
            csrc[it] = Bt + (size_t)(n0 + (boff >> 6)) * K + ((boff & 63) >> 1);
            cdst[it] = lB + (boff >> 1);
        }
    }

    for (int k0 = kbeg; k0 < kend; k0 += 32) {
        __syncthreads();
#pragma unroll
        for (int it = 0; it < 3; ++it)
            __builtin_amdgcn_global_load_lds((const AS1 void*)(csrc[it] + k0),
                                             (AS3 void*)cdst[it], 16, 0, 0);
        __builtin_amdgcn_s_waitcnt(0);
        __syncthreads();

        bf16x8 af[2], bfr[4];
#pragma unroll
        for (int i = 0; i < 2; ++i) af[i] = *(const bf16x8*)&lA[(wm + i * 16 + l16) * 32 + quad * 8];
#pragma unroll
        for (int j = 0; j < 4; ++j) bfr[j] = *(const bf16x8*)&lB[(wn + j * 16 + l16) * 32 + quad * 8];
#pragma unroll
        for (int i = 0; i < 2; ++i)
#pragma unroll
            for (int j = 0; j < 4; ++j)
                acc[i][j] = __builtin_amdgcn_mfma_f32_16x16x32_bf16(af[i], bfr[j], acc[i][j], 0, 0, 0);
    }
#pragma unroll
    for (int i = 0; i < 2; ++i)
#pragma unroll
        for (int j = 0; j < 4; ++j) {
            const int row = m0 + wm + i * 16 + quad * 4;
            const int col = n0 + wn + j * 16 + l16;
#pragma unroll
            for (int r = 0; r < 4; ++r)
                C[(size_t)(row + r) * N + col] = acc[i][j][r];
        }
}

// ------------------------------------------------- out += partial (deterministic split-K reduce)
__global__ __launch_bounds__(256) void reduce_add(float4* __restrict__ out, const float4* __restrict__ p) {
    const int i = blockIdx.x * 256 + threadIdx.x;
    float4 a = out[i];
    const float4 b = p[i];
    a.x += b.x; a.y += b.y; a.z += b.z; a.w += b.w;
    out[i] = a;
}

// ------------------------------------------------- flash attention: no-P-LDS + 8-wave split-K + LDS dbuf
// (R8 version, verified 44.9 us.)
__global__ __launch_bounds__(512, 4) void flash_attn(const __bf16* __restrict__ Qr, const __bf16* __restrict__ Kr,
                                                     const __bf16* __restrict__ Vt, __bf16* __restrict__ O) {
    constexpr int S = 2048;
    __shared__ __align__(16) __bf16 smem[2][4 * 64 * 72];   // 73728 B, 2 buffers
    const int qt = blockIdx.x, h = blockIdx.y, kvh = h >> 2;
    const int tid = threadIdx.x, wave = tid >> 6, lane = tid & 63;
    const int grp = wave >> 2, w4 = wave & 3;
    const int l32 = lane & 31, hi = lane >> 5;
    const int goff = grp * 2 * 4608;

    const int qrow = qt * 128 + w4 * 32 + l32;
    const __bf16* qptr = Qr + ((size_t)h * S + qrow) * 64;
    bf16x8 qf[4];
#pragma unroll
    for (int kc = 0; kc < 4; ++kc) qf[kc] = *(const bf16x8*)(qptr + kc * 16 + hi * 8);

    const __bf16* Kbase = Kr + (size_t)kvh * S * 64;
    const __bf16* Vbase = Vt + (size_t)kvh * 64 * S;

    const int gtid = tid & 255;
    const int krow = gtid >> 3;
    const int kcol = (gtid & 7) * 8;
    const int vslot = (kcol & 48) | ((kcol & 8) >> 1);

    bf16x8 kreg0 = *(const bf16x8*)(Kbase + (size_t)(grp * 64 + krow) * 64 + kcol);
    bf16x8 kreg1 = *(const bf16x8*)(Kbase + (size_t)(grp * 64 + 32 + krow) * 64 + kcol);
    bf16x8 vreg0 = *(const bf16x8*)(Vbase + (size_t)krow * S + grp * 64 + kcol);
    bf16x8 vreg1 = *(const bf16x8*)(Vbase + (size_t)(32 + krow) * S + grp * 64 + kcol);

    fx16 ov0, ov1;
#pragma unroll
    for (int i = 0; i < 16; ++i) { ov0[i] = 0.f; ov1[i] = 0.f; }
    float l_acc = 0.f;

    {
        __bf16* nK = &smem[0][goff];
        __bf16* nV = nK + 4608;
        *(bf16x8*)&nK[krow * 72 + kcol] = kreg0;
        *(bf16x8*)&nK[(32 + krow) * 72 + kcol] = kreg1;
        bf16x4 v0lo = { vreg0[0], vreg0[1], vreg0[2], vreg0[3] };
        bf16x4 v0hi = { vreg0[4], vreg0[5], vreg0[6], vreg0[7] };
        bf16x4 v1lo = { vreg1[0], vreg1[1], vreg1[2], vreg1[3] };
        bf16x4 v1hi = { vreg1[4], vreg1[5], vreg1[6], vreg1[7] };
        *(bf16x4*)&nV[krow * 72 + vslot]            = v0lo;
        *(bf16x4*)&nV[krow * 72 + vslot + 8]        = v0hi;
        *(bf16x4*)&nV[(32 + krow) * 72 + vslot]     = v1lo;
        *(bf16x4*)&nV[(32 + krow) * 72 + vslot + 8] = v1hi;
        const int kt1 = 2 + grp;
        kreg0 = *(const bf16x8*)(Kbase + (size_t)(kt1 * 64 + krow) * 64 + kcol);
        kreg1 = *(const bf16x8*)(Kbase + (size_t)(kt1 * 64 + 32 + krow) * 64 + kcol);
        vreg0 = *(const bf16x8*)(Vbase + (size_t)krow * S + kt1 * 64 + kcol);
        vreg1 = *(const bf16x8*)(Vbase + (size_t)(32 + krow) * S + kt1 * 64 + kcol);
    }
    __syncthreads();

    for (int it = 0; it < 16; ++it) {
        __bf16* lKg = &smem[it & 1][goff];
        __bf16* lVg = lKg + 4608;

        if (it + 1 < 16) {
            __bf16* nK = &smem[(it + 1) & 1][goff];
            __bf16* nV = nK + 4608;
            *(bf16x8*)&nK[krow * 72 + kcol] = kreg0;
            *(bf16x8*)&nK[(32 + krow) * 72 + kcol] = kreg1;
            bf16x4 v0lo = { vreg0[0], vreg0[1], vreg0[2], vreg0[3] };
            bf16x4 v0hi = { vreg0[4], vreg0[5], vreg0[6], vreg0[7] };
            bf16x4 v1lo = { vreg1[0], vreg1[1], vreg1[2], vreg1[3] };
            bf16x4 v1hi = { vreg1[4], vreg1[5], vreg1[6], vreg1[7] };
            *(bf16x4*)&nV[krow * 72 + vslot]            = v0lo;
            *(bf16x4*)&nV[krow * 72 + vslot + 8]        = v0hi;
            *(bf16x4*)&nV[(32 + krow) * 72 + vslot]     = v1lo;
            *(bf16x4*)&nV[(32 + krow) * 72 + vslot + 8] = v1hi;
            const int it2 = (it + 2 < 16) ? it + 2 : 15;
            const int ktn = it2 * 2 + grp;
            kreg0 = *(const bf16x8*)(Kbase + (size_t)(ktn * 64 + krow) * 64 + kcol);
            kreg1 = *(const bf16x8*)(Kbase + (size_t)(ktn * 64 + 32 + krow) * 64 + kcol);
            vreg0 = *(const bf16x8*)(Vbase + (size_t)krow * S + ktn * 64 + kcol);
            vreg1 = *(const bf16x8*)(Vbase + (size_t)(32 + krow) * S + ktn * 64 + kcol);
        }

        fx16 sc0, sc1;
#pragma unroll
        for (int i = 0; i < 16; ++i) { sc0[i] = 0.f; sc1[i] = 0.f; }
#pragma unroll
        for (int kc = 0; kc < 4; ++kc) {
            const bf16x8 a0 = *(const bf16x8*)&lKg[l32 * 72 + kc * 16 + hi * 8];
            const bf16x8 a1 = *(const bf16x8*)&lKg[(32 + l32) * 72 + kc * 16 + hi * 8];
            sc0 = __builtin_amdgcn_mfma_f32_32x32x16_bf16(a0, qf[kc], sc0, 0, 0, 0);
            sc1 = __builtin_amdgcn_mfma_f32_32x32x16_bf16(a1, qf[kc], sc1, 0, 0, 0);
        }

#pragma unroll
        for (int h2 = 0; h2 < 2; ++h2) {
#pragma unroll
            for (int c = 0; c < 2; ++c) {
                bf16x8 pb;
#pragma unroll
                for (int j = 0; j < 8; ++j) {
                    const float sv = h2 ? sc1[c * 8 + j] : sc0[c * 8 + j];
                    const float p = __builtin_amdgcn_exp2f(sv);
                    l_acc += p;
                    pb[j] = (__bf16)p;
                }
                const int kcv = h2 * 2 + c;
                const bf16x8 va0 = *(const bf16x8*)&lVg[l32 * 72 + kcv * 16 + hi * 8];
                const bf16x8 va1 = *(const bf16x8*)&lVg[(32 + l32) * 72 + kcv * 16 + hi * 8];
                ov0 = __builtin_amdgcn_mfma_f32_32x32x16_bf16(va0, pb, ov0, 0, 0, 0);
                ov1 = __builtin_amdgcn_mfma_f32_32x32x16_bf16(va1, pb, ov1, 0, 0, 0);
            }
        }
        __syncthreads();
    }

    const float l_pair = l_acc + __shfl_xor(l_acc, 32, 64);

    fx4* lO = (fx4*)&smem[0][0];
    float* lL = (float*)(&smem[0][0] + 16384);   // byte 32768
    if (grp == 1) {
#pragma unroll
        for (int ic = 0; ic < 4; ++ic) {
            fx4 c0, c1;
#pragma unroll
            for (int r = 0; r < 4; ++r) { c0[r] = ov0[ic * 4 + r]; c1[r] = ov1[ic * 4 + r]; }
            lO[(ic * 4 + w4) * 64 + lane] = c0;
            lO[((ic + 4) * 4 + w4) * 64 + lane] = c1;
        }
        if (hi == 0) lL[w4 * 32 + l32] = l_pair;
    }
    __syncthreads();
    if (grp == 0) {
#pragma unroll
        for (int ic = 0; ic < 4; ++ic) {
            const fx4 c0 = lO[(ic * 4 + w4) * 64 + lane];
            const fx4 c1 = lO[((ic + 4) * 4 + w4) * 64 + lane];
#pragma unroll
            for (int r = 0; r < 4; ++r) { ov0[ic * 4 + r] += c0[r]; ov1[ic * 4 + r] += c1[r]; }
        }
        const float inv_l = 1.0f / (l_pair + lL[w4 * 32 + l32]);
#pragma unroll
        for (int dt = 0; dt < 2; ++dt)
#pragma unroll
            for (int rg2 = 0; rg2 < 4; ++rg2) {
                bf16x4 o4;
#pragma unroll
                for (int r = 0; r < 4; ++r)
                    o4[r] = (__bf16)((dt ? ov1[rg2 * 4 + r] : ov0[rg2 * 4 + r]) * inv_l);
                const int col = h * 64 + dt * 32 + rg2 * 8 + hi * 4;
                *(bf16x4*)(O + (size_t)qrow * 2048 + col) = o4;
            }
    }
}

// ----------------------------------------------------------------------------
extern "C" void kernel_launch(void* const* d_in, const int* in_sizes, int n_in,
                              void* d_out, int out_size, void* d_ws, size_t ws_size,
                              hipStream_t stream) {
    const float* x  = (const float*)d_in[0];
    const float* wq = (const float*)d_in[1];
    const float* wk = (const float*)d_in[2];
    const float* wv = (const float*)d_in[3];
    const float* wo = (const float*)d_in[4];
    float* out = (float*)d_out;
    char* ws = (char*)d_ws;

    __bf16* Xb    = (__bf16*)ws;                        // [0, 8M)
    __bf16* WqkvT = (__bf16*)(ws + ((size_t)8 << 20));  // [8M, 20M)  3072 x 2048
    __bf16* WoT   = (__bf16*)(ws + ((size_t)20 << 20)); // [20M, 28M) 2048 x 2048
    __bf16* Qr    = (__bf16*)(ws + ((size_t)28 << 20)); // [28M, 36M) 32 x 2048 x 64
    __bf16* Kr    = (__bf16*)(ws + ((size_t)36 << 20)); // [36M, 38M)  8 x 2048 x 64
    __bf16* Vt    = (__bf16*)(ws + ((size_t)38 << 20)); // [38M, 40M)  8 x 64 x 2048
    __bf16* Ob    = (__bf16*)(ws + ((size_t)40 << 20)); // [40M, 48M) 2048 x 2048
    float*  Cp    = (float*)ws;                         // [0, 16.8M) split-K partial (Xb/WqkvT dead)

    prep<<<14336, 256, 0, stream>>>((const float4*)x, Xb, wq, wk, wv, wo, WqkvT, WoT);
    gemm_qkv<<<dim3(32, 48), 256, 0, stream>>>(Xb, WqkvT, Qr, Kr, Vt);
    flash_attn<<<dim3(16, 32), 512, 0, stream>>>(Qr, Kr, Vt, Ob);
    gemm_bt_sk<<<dim3(32, 16, 2), 256, 0, stream>>>(Ob, WoT, out, Cp, 2048, 2048, 2048);
    reduce_add<<<4096, 256, 0, stream>>>((float4*)out, (const float4*)Cp);
}

// Round 13
// 225.396 us; speedup vs baseline: 1.0884x; 1.0253x over previous
//
#include <hip/hip_runtime.h>
#include <hip/hip_bf16.h>

typedef __bf16 bf16x8 __attribute__((ext_vector_type(8)));
typedef __bf16 bf16x4 __attribute__((ext_vector_type(4)));
typedef float fx4 __attribute__((ext_vector_type(4)));
typedef float fx16 __attribute__((ext_vector_type(16)));

#define AS1 __attribute__((address_space(1)))
#define AS3 __attribute__((address_space(3)))

// ------------------------------------------------- prep: cast x->bf16 + all 4 weight transposes
__global__ __launch_bounds__(256) void prep(const float4* __restrict__ X, __bf16* __restrict__ Xb,
                                            const float* __restrict__ wq, const float* __restrict__ wk,
                                            const float* __restrict__ wv, const float* __restrict__ wo,
                                            __bf16* __restrict__ WqkvT, __bf16* __restrict__ WoT) {
    constexpr int K = 2048;
    __shared__ float t[32][33];
    const int bx = blockIdx.x;
    if (bx < 4096) {
        const int i = bx * 256 + threadIdx.x;
        float4 v = X[i];
        bf16x4 o = { (__bf16)v.x, (__bf16)v.y, (__bf16)v.z, (__bf16)v.w };
        *(bf16x4*)(Xb + (size_t)i * 4) = o;
        return;
    }
    const int r = bx - 4096;
    const int tbx = r % 160, tby = r / 160;
    const float* W; __bf16* Wt; int N, n0;
    if (tbx < 64)      { W = wq; Wt = WqkvT;                        N = 2048; n0 = tbx * 32; }
    else if (tbx < 80) { W = wk; Wt = WqkvT + (size_t)2048 * 2048;  N = 512;  n0 = (tbx - 64) * 32; }
    else if (tbx < 96) { W = wv; Wt = WqkvT + (size_t)2560 * 2048;  N = 512;  n0 = (tbx - 80) * 32; }
    else               { W = wo; Wt = WoT;                          N = 2048; n0 = (tbx - 96) * 32; }
    const int tx = threadIdx.x & 31, ty = threadIdx.x >> 5;
    const int k0 = tby * 32;
#pragma unroll
    for (int i = 0; i < 4; ++i)
        t[ty + i * 8][tx] = W[(size_t)(k0 + ty + i * 8) * N + n0 + tx];
    __syncthreads();
#pragma unroll
    for (int i = 0; i < 4; ++i)
        Wt[(size_t)(n0 + ty + i * 8) * K + k0 + tx] = (__bf16)t[tx][ty + i * 8];
}

// ------------------------------------------------- QKV GEMM, BM=128, BN=64, BK=64, fused RoPE/split
// (R8 config -- part of the measured-best 221 us total.) grid (16, 48) = 768 blocks, 3/CU.
__global__ __launch_bounds__(256) void gemm_qkv(const __bf16* __restrict__ A, const __bf16* __restrict__ Bt,
                                                __bf16* __restrict__ Qr, __bf16* __restrict__ Kr,
                                                __bf16* __restrict__ Vt) {
    constexpr int K = 2048;
    __shared__ __align__(16) __bf16 lA[2][128 * 32];
    __shared__ __align__(16) __bf16 lB[2][64 * 32];
    const int tid = threadIdx.x;
    const int wave = tid >> 6, lane = tid & 63;
    const int quad = lane >> 4, l16 = lane & 15;
    const int m0 = blockIdx.x * 128, n0 = blockIdx.y * 64;
    fx4 acc[2][4] = {};

    const __bf16* csrc[6]; __bf16* cdst[6];
#pragma unroll
    for (int it = 0; it < 6; ++it) {
        const int idx = wave * 6 + it;
        const int r4 = lane >> 2, c8 = (lane & 3) * 8;
        if (idx < 16) {
            const int kh = idx & 1, s = idx >> 1;
            csrc[it] = A + (size_t)(m0 + s * 16 + r4) * K + kh * 32 + c8;
            cdst[it] = &lA[kh][s * 512 + lane * 8];
        } else {
            const int b = idx - 16, kh = b & 1, s = b >> 1;
            csrc[it] = Bt + (size_t)(n0 + s * 16 + r4) * K + kh * 32 + c8;
            cdst[it] = &lB[kh][s * 512 + lane * 8];
        }
    }

    for (int k0 = 0; k0 < K; k0 += 64) {
        __syncthreads();
#pragma unroll
        for (int it = 0; it < 6; ++it)
            __builtin_amdgcn_global_load_lds((const AS1 void*)(csrc[it] + k0),
                                             (AS3 void*)cdst[it], 16, 0, 0);
        __builtin_amdgcn_s_waitcnt(0);
        __syncthreads();

#pragma unroll
        for (int kc = 0; kc < 2; ++kc) {
            bf16x8 af[2], bfr[4];
#pragma unroll
            for (int i = 0; i < 2; ++i) af[i] = *(const bf16x8*)&lA[kc][(wave * 32 + i * 16 + l16) * 32 + quad * 8];
#pragma unroll
            for (int j = 0; j < 4; ++j) bfr[j] = *(const bf16x8*)&lB[kc][(j * 16 + l16) * 32 + quad * 8];
#pragma unroll
            for (int i = 0; i < 2; ++i)
#pragma unroll
                for (int j = 0; j < 4; ++j)
                    acc[i][j] = __builtin_amdgcn_mfma_f32_16x16x32_bf16(af[i], bfr[j], acc[i][j], 0, 0, 0);
        }
    }

    const int by = blockIdx.y;
    if (by < 40) {
        const float scale = (by < 32) ? 0.18033688011112042f : 1.0f;   // Q: 0.125*log2(e)
        __bf16* base = (by < 32) ? (Qr + (size_t)by * 2048 * 64)
                                 : (Kr + (size_t)(by - 32) * 2048 * 64);
#pragma unroll
        for (int jj = 0; jj < 2; ++jj) {
            const int dlo = jj * 16 + l16;
            const float inv = __builtin_amdgcn_exp2f(-(float)dlo * 0.41524101186092029f);
#pragma unroll
            for (int i = 0; i < 2; ++i)
#pragma unroll
                for (int r = 0; r < 4; ++r) {
                    const int s = m0 + wave * 32 + i * 16 + quad * 4 + r;
                    float sn, cs;
                    __sincosf((float)s * inv, &sn, &cs);
                    const float lo = acc[i][jj][r], hv = acc[i][jj + 2][r];
                    base[(size_t)s * 64 + dlo]      = (__bf16)((lo * cs - hv * sn) * scale);
                    base[(size_t)s * 64 + dlo + 32] = (__bf16)((hv * cs + lo * sn) * scale);
                }
        }
    } else {
        __bf16* vb = Vt + (size_t)(by - 40) * 64 * 2048;
#pragma unroll
        for (int i = 0; i < 2; ++i)
#pragma unroll
            for (int j = 0; j < 4; ++j) {
                const int d = j * 16 + l16;
                const int s0 = m0 + wave * 32 + i * 16 + quad * 4;
                bf16x4 p;
#pragma unroll
                for (int r = 0; r < 4; ++r) p[r] = (__bf16)acc[i][j][r];
                *(bf16x4*)&vb[(size_t)d * 2048 + s0] = p;
            }
    }
}

// ------------------------------------------------- out-projection GEMM, BM=64, BN=128, NO split-K
// grid (32, 16) = 512 blocks = 2 blocks/CU (the measured ~600 TF operating point).
// Writes d_out directly -- no partial, no reduce launch.
__global__ __launch_bounds__(256) void gemm_bt(const __bf16* __restrict__ A, const __bf16* __restrict__ Bt,
                                               float* __restrict__ C, int M, int N, int K) {
    __shared__ __align__(16) __bf16 lA[64 * 32];
    __shared__ __align__(16) __bf16 lB[128 * 32];
    const int tid = threadIdx.x;
    const int wave = tid >> 6, lane = tid & 63;
    const int quad = lane >> 4, l16 = lane & 15;
    const int m0 = blockIdx.x * 64, n0 = blockIdx.y * 128;
    const int wm = (wave >> 1) * 32, wn = (wave & 1) * 64;
    fx4 acc[2][4] = {};

    // 12 chunks of 1KB (A: 0..3, B: 4..11); 3 per wave
    const __bf16* csrc[3]; __bf16* cdst[3];
#pragma unroll
    for (int it = 0; it < 3; ++it) {
        const int idx = wave * 3 + it;
        if (idx < 4) {
            const int boff = idx * 1024 + lane * 16;
            csrc[it] = A + (size_t)(m0 + (boff >> 6)) * K + ((boff & 63) >> 1);
            cdst[it] = lA + (boff >> 1);
        } else {
            const int boff = (idx - 4) * 1024 + lane * 16;
            csrc[it] = Bt + (size_t)(n0 + (boff >> 6)) * K + ((boff & 63) >> 1);
            cdst[it] = lB + (boff >> 1);
        }
    }

    for (int k0 = 0; k0 < K; k0 += 32) {
        __syncthreads();
#pragma unroll
        for (int it = 0; it < 3; ++it)
            __builtin_amdgcn_global_load_lds((const AS1 void*)(csrc[it] + k0),
                                             (AS3 void*)cdst[it], 16, 0, 0);
        __builtin_amdgcn_s_waitcnt(0);
        __syncthreads();

        bf16x8 af[2], bfr[4];
#pragma unroll
        for (int i = 0; i < 2; ++i) af[i] = *(const bf16x8*)&lA[(wm + i * 16 + l16) * 32 + quad * 8];
#pragma unroll
        for (int j = 0; j < 4; ++j) bfr[j] = *(const bf16x8*)&lB[(wn + j * 16 + l16) * 32 + quad * 8];
#pragma unroll
        for (int i = 0; i < 2; ++i)
#pragma unroll
            for (int j = 0; j < 4; ++j)
                acc[i][j] = __builtin_amdgcn_mfma_f32_16x16x32_bf16(af[i], bfr[j], acc[i][j], 0, 0, 0);
    }
#pragma unroll
    for (int i = 0; i < 2; ++i)
#pragma unroll
        for (int j = 0; j < 4; ++j) {
            const int row = m0 + wm + i * 16 + quad * 4;
            const int col = n0 + wn + j * 16 + l16;
#pragma unroll
            for (int r = 0; r < 4; ++r)
                C[(size_t)(row + r) * N + col] = acc[i][j][r];
        }
}

// ------------------------------------------------- flash attention: no-P-LDS + 8-wave split-K + LDS dbuf
// (R8 version, verified 44.9 us -- structural plateau, accepted.)
__global__ __launch_bounds__(512, 4) void flash_attn(const __bf16* __restrict__ Qr, const __bf16* __restrict__ Kr,
                                                     const __bf16* __restrict__ Vt, __bf16* __restrict__ O) {
    constexpr int S = 2048;
    __shared__ __align__(16) __bf16 smem[2][4 * 64 * 72];   // 73728 B, 2 buffers
    const int qt = blockIdx.x, h = blockIdx.y, kvh = h >> 2;
    const int tid = threadIdx.x, wave = tid >> 6, lane = tid & 63;
    const int grp = wave >> 2, w4 = wave & 3;
    const int l32 = lane & 31, hi = lane >> 5;
    const int goff = grp * 2 * 4608;

    const int qrow = qt * 128 + w4 * 32 + l32;
    const __bf16* qptr = Qr + ((size_t)h * S + qrow) * 64;
    bf16x8 qf[4];
#pragma unroll
    for (int kc = 0; kc < 4; ++kc) qf[kc] = *(const bf16x8*)(qptr + kc * 16 + hi * 8);

    const __bf16* Kbase = Kr + (size_t)kvh * S * 64;
    const __bf16* Vbase = Vt + (size_t)kvh * 64 * S;

    const int gtid = tid & 255;
    const int krow = gtid >> 3;
    const int kcol = (gtid & 7) * 8;
    const int vslot = (kcol & 48) | ((kcol & 8) >> 1);

    bf16x8 kreg0 = *(const bf16x8*)(Kbase + (size_t)(grp * 64 + krow) * 64 + kcol);
    bf16x8 kreg1 = *(const bf16x8*)(Kbase + (size_t)(grp * 64 + 32 + krow) * 64 + kcol);
    bf16x8 vreg0 = *(const bf16x8*)(Vbase + (size_t)krow * S + grp * 64 + kcol);
    bf16x8 vreg1 = *(const bf16x8*)(Vbase + (size_t)(32 + krow) * S + grp * 64 + kcol);

    fx16 ov0, ov1;
#pragma unroll
    for (int i = 0; i < 16; ++i) { ov0[i] = 0.f; ov1[i] = 0.f; }
    float l_acc = 0.f;

    {
        __bf16* nK = &smem[0][goff];
        __bf16* nV = nK + 4608;
        *(bf16x8*)&nK[krow * 72 + kcol] = kreg0;
        *(bf16x8*)&nK[(32 + krow) * 72 + kcol] = kreg1;
        bf16x4 v0lo = { vreg0[0], vreg0[1], vreg0[2], vreg0[3] };
        bf16x4 v0hi = { vreg0[4], vreg0[5], vreg0[6], vreg0[7] };
        bf16x4 v1lo = { vreg1[0], vreg1[1], vreg1[2], vreg1[3] };
        bf16x4 v1hi = { vreg1[4], vreg1[5], vreg1[6], vreg1[7] };
        *(bf16x4*)&nV[krow * 72 + vslot]            = v0lo;
        *(bf16x4*)&nV[krow * 72 + vslot + 8]        = v0hi;
        *(bf16x4*)&nV[(32 + krow) * 72 + vslot]     = v1lo;
        *(bf16x4*)&nV[(32 + krow) * 72 + vslot + 8] = v1hi;
        const int kt1 = 2 + grp;
        kreg0 = *(const bf16x8*)(Kbase + (size_t)(kt1 * 64 + krow) * 64 + kcol);
        kreg1 = *(const bf16x8*)(Kbase + (size_t)(kt1 * 64 + 32 + krow) * 64 + kcol);
        vreg0 = *(const bf16x8*)(Vbase + (size_t)krow * S + kt1 * 64 + kcol);
        vreg1 = *(const bf16x8*)(Vbase + (size_t)(32 + krow) * S + kt1 * 64 + kcol);
    }
    __syncthreads();

    for (int it = 0; it < 16; ++it) {
        __bf16* lKg = &smem[it & 1][goff];
        __bf16* lVg = lKg + 4608;

        if (it + 1 < 16) {
            __bf16* nK = &smem[(it + 1) & 1][goff];
            __bf16* nV = nK + 4608;
            *(bf16x8*)&nK[krow * 72 + kcol] = kreg0;
            *(bf16x8*)&nK[(32 + krow) * 72 + kcol] = kreg1;
            bf16x4 v0lo = { vreg0[0], vreg0[1], vreg0[2], vreg0[3] };
            bf16x4 v0hi = { vreg0[4], vreg0[5], vreg0[6], vreg0[7] };
            bf16x4 v1lo = { vreg1[0], vreg1[1], vreg1[2], vreg1[3] };
            bf16x4 v1hi = { vreg1[4], vreg1[5], vreg1[6], vreg1[7] };
            *(bf16x4*)&nV[krow * 72 + vslot]            = v0lo;
            *(bf16x4*)&nV[krow * 72 + vslot + 8]        = v0hi;
            *(bf16x4*)&nV[(32 + krow) * 72 + vslot]     = v1lo;
            *(bf16x4*)&nV[(32 + krow) * 72 + vslot + 8] = v1hi;
            const int it2 = (it + 2 < 16) ? it + 2 : 15;
            const int ktn = it2 * 2 + grp;
            kreg0 = *(const bf16x8*)(Kbase + (size_t)(ktn * 64 + krow) * 64 + kcol);
            kreg1 = *(const bf16x8*)(Kbase + (size_t)(ktn * 64 + 32 + krow) * 64 + kcol);
            vreg0 = *(const bf16x8*)(Vbase + (size_t)krow * S + ktn * 64 + kcol);
            vreg1 = *(const bf16x8*)(Vbase + (size_t)(32 + krow) * S + ktn * 64 + kcol);
        }

        fx16 sc0, sc1;
#pragma unroll
        for (int i = 0; i < 16; ++i) { sc0[i] = 0.f; sc1[i] = 0.f; }
#pragma unroll
        for (int kc = 0; kc < 4; ++kc) {
            const bf16x8 a0 = *(const bf16x8*)&lKg[l32 * 72 + kc * 16 + hi * 8];
            const bf16x8 a1 = *(const bf16x8*)&lKg[(32 + l32) * 72 + kc * 16 + hi * 8];
            sc0 = __builtin_amdgcn_mfma_f32_32x32x16_bf16(a0, qf[kc], sc0, 0, 0, 0);
            sc1 = __builtin_amdgcn_mfma_f32_32x32x16_bf16(a1, qf[kc], sc1, 0, 0, 0);
        }

#pragma unroll
        for (int h2 = 0; h2 < 2; ++h2) {
#pragma unroll
            for (int c = 0; c < 2; ++c) {
                bf16x8 pb;
#pragma unroll
                for (int j = 0; j < 8; ++j) {
                    const float sv = h2 ? sc1[c * 8 + j] : sc0[c * 8 + j];
                    const float p = __builtin_amdgcn_exp2f(sv);
                    l_acc += p;
                    pb[j] = (__bf16)p;
                }
                const int kcv = h2 * 2 + c;
                const bf16x8 va0 = *(const bf16x8*)&lVg[l32 * 72 + kcv * 16 + hi * 8];
                const bf16x8 va1 = *(const bf16x8*)&lVg[(32 + l32) * 72 + kcv * 16 + hi * 8];
                ov0 = __builtin_amdgcn_mfma_f32_32x32x16_bf16(va0, pb, ov0, 0, 0, 0);
                ov1 = __builtin_amdgcn_mfma_f32_32x32x16_bf16(va1, pb, ov1, 0, 0, 0);
            }
        }
        __syncthreads();
    }

    const float l_pair = l_acc + __shfl_xor(l_acc, 32, 64);

    fx4* lO = (fx4*)&smem[0][0];
    float* lL = (float*)(&smem[0][0] + 16384);   // byte 32768
    if (grp == 1) {
#pragma unroll
        for (int ic = 0; ic < 4; ++ic) {
            fx4 c0, c1;
#pragma unroll
            for (int r = 0; r < 4; ++r) { c0[r] = ov0[ic * 4 + r]; c1[r] = ov1[ic * 4 + r]; }
            lO[(ic * 4 + w4) * 64 + lane] = c0;
            lO[((ic + 4) * 4 + w4) * 64 + lane] = c1;
        }
        if (hi == 0) lL[w4 * 32 + l32] = l_pair;
    }
    __syncthreads();
    if (grp == 0) {
#pragma unroll
        for (int ic = 0; ic < 4; ++ic) {
            const fx4 c0 = lO[(ic * 4 + w4) * 64 + lane];
            const fx4 c1 = lO[((ic + 4) * 4 + w4) * 64 + lane];
#pragma unroll
            for (int r = 0; r < 4; ++r) { ov0[ic * 4 + r] += c0[r]; ov1[ic * 4 + r] += c1[r]; }
        }
        const float inv_l = 1.0f / (l_pair + lL[w4 * 32 + l32]);
#pragma unroll
        for (int dt = 0; dt < 2; ++dt)
#pragma unroll
            for (int rg2 = 0; rg2 < 4; ++rg2) {
                bf16x4 o4;
#pragma unroll
                for (int r = 0; r < 4; ++r)
                    o4[r] = (__bf16)((dt ? ov1[rg2 * 4 + r] : ov0[rg2 * 4 + r]) * inv_l);
                const int col = h * 64 + dt * 32 + rg2 * 8 + hi * 4;
                *(bf16x4*)(O + (size_t)qrow * 2048 + col) = o4;
            }
    }
}

// ----------------------------------------------------------------------------
extern "C" void kernel_launch(void* const* d_in, const int* in_sizes, int n_in,
                              void* d_out, int out_size, void* d_ws, size_t ws_size,
                              hipStream_t stream) {
    const float* x  = (const float*)d_in[0];
    const float* wq = (const float*)d_in[1];
    const float* wk = (const float*)d_in[2];
    const float* wv = (const float*)d_in[3];
    const float* wo = (const float*)d_in[4];
    float* out = (float*)d_out;
    char* ws = (char*)d_ws;

    __bf16* Xb    = (__bf16*)ws;                        // [0, 8M)
    __bf16* WqkvT = (__bf16*)(ws + ((size_t)8 << 20));  // [8M, 20M)  3072 x 2048
    __bf16* WoT   = (__bf16*)(ws + ((size_t)20 << 20)); // [20M, 28M) 2048 x 2048
    __bf16* Qr    = (__bf16*)(ws + ((size_t)28 << 20)); // [28M, 36M) 32 x 2048 x 64
    __bf16* Kr    = (__bf16*)(ws + ((size_t)36 << 20)); // [36M, 38M)  8 x 2048 x 64
    __bf16* Vt    = (__bf16*)(ws + ((size_t)38 << 20)); // [38M, 40M)  8 x 64 x 2048
    __bf16* Ob    = (__bf16*)(ws + ((size_t)40 << 20)); // [40M, 48M) 2048 x 2048

    prep<<<14336, 256, 0, stream>>>((const float4*)x, Xb, wq, wk, wv, wo, WqkvT, WoT);
    gemm_qkv<<<dim3(16, 48), 256, 0, stream>>>(Xb, WqkvT, Qr, Kr, Vt);
    flash_attn<<<dim3(16, 32), 512, 0, stream>>>(Qr, Kr, Vt, Ob);
    gemm_bt<<<dim3(32, 16), 256, 0, stream>>>(Ob, WoT, out, 2048, 2048, 2048);
}

// Round 14
// 222.350 us; speedup vs baseline: 1.1034x; 1.0137x over previous
//
#include <hip/hip_runtime.h>
#include <hip/hip_bf16.h>

typedef __bf16 bf16x8 __attribute__((ext_vector_type(8)));
typedef __bf16 bf16x4 __attribute__((ext_vector_type(4)));
typedef float fx4 __attribute__((ext_vector_type(4)));
typedef float fx16 __attribute__((ext_vector_type(16)));

#define AS1 __attribute__((address_space(1)))
#define AS3 __attribute__((address_space(3)))

// ------------------------------------------------- prep: cast x->bf16 + all 4 weight transposes
__global__ __launch_bounds__(256) void prep(const float4* __restrict__ X, __bf16* __restrict__ Xb,
                                            const float* __restrict__ wq, const float* __restrict__ wk,
                                            const float* __restrict__ wv, const float* __restrict__ wo,
                                            __bf16* __restrict__ WqkvT, __bf16* __restrict__ WoT) {
    constexpr int K = 2048;
    __shared__ float t[32][33];
    const int bx = blockIdx.x;
    if (bx < 4096) {
        const int i = bx * 256 + threadIdx.x;
        float4 v = X[i];
        bf16x4 o = { (__bf16)v.x, (__bf16)v.y, (__bf16)v.z, (__bf16)v.w };
        *(bf16x4*)(Xb + (size_t)i * 4) = o;
        return;
    }
    const int r = bx - 4096;
    const int tbx = r % 160, tby = r / 160;
    const float* W; __bf16* Wt; int N, n0;
    if (tbx < 64)      { W = wq; Wt = WqkvT;                        N = 2048; n0 = tbx * 32; }
    else if (tbx < 80) { W = wk; Wt = WqkvT + (size_t)2048 * 2048;  N = 512;  n0 = (tbx - 64) * 32; }
    else if (tbx < 96) { W = wv; Wt = WqkvT + (size_t)2560 * 2048;  N = 512;  n0 = (tbx - 80) * 32; }
    else               { W = wo; Wt = WoT;                          N = 2048; n0 = (tbx - 96) * 32; }
    const int tx = threadIdx.x & 31, ty = threadIdx.x >> 5;
    const int k0 = tby * 32;
#pragma unroll
    for (int i = 0; i < 4; ++i)
        t[ty + i * 8][tx] = W[(size_t)(k0 + ty + i * 8) * N + n0 + tx];
    __syncthreads();
#pragma unroll
    for (int i = 0; i < 4; ++i)
        Wt[(size_t)(n0 + ty + i * 8) * K + k0 + tx] = (__bf16)t[tx][ty + i * 8];
}

// ------------------------------------------------- QKV GEMM, BM=128, BN=64, BK=64, fused RoPE/split
// (measured-best config) grid (16, 48) = 768 blocks, 3/CU.
__global__ __launch_bounds__(256) void gemm_qkv(const __bf16* __restrict__ A, const __bf16* __restrict__ Bt,
                                                __bf16* __restrict__ Qr, __bf16* __restrict__ Kr,
                                                __bf16* __restrict__ Vt) {
    constexpr int K = 2048;
    __shared__ __align__(16) __bf16 lA[2][128 * 32];
    __shared__ __align__(16) __bf16 lB[2][64 * 32];
    const int tid = threadIdx.x;
    const int wave = tid >> 6, lane = tid & 63;
    const int quad = lane >> 4, l16 = lane & 15;
    const int m0 = blockIdx.x * 128, n0 = blockIdx.y * 64;
    fx4 acc[2][4] = {};

    const __bf16* csrc[6]; __bf16* cdst[6];
#pragma unroll
    for (int it = 0; it < 6; ++it) {
        const int idx = wave * 6 + it;
        const int r4 = lane >> 2, c8 = (lane & 3) * 8;
        if (idx < 16) {
            const int kh = idx & 1, s = idx >> 1;
            csrc[it] = A + (size_t)(m0 + s * 16 + r4) * K + kh * 32 + c8;
            cdst[it] = &lA[kh][s * 512 + lane * 8];
        } else {
            const int b = idx - 16, kh = b & 1, s = b >> 1;
            csrc[it] = Bt + (size_t)(n0 + s * 16 + r4) * K + kh * 32 + c8;
            cdst[it] = &lB[kh][s * 512 + lane * 8];
        }
    }

    for (int k0 = 0; k0 < K; k0 += 64) {
        __syncthreads();
#pragma unroll
        for (int it = 0; it < 6; ++it)
            __builtin_amdgcn_global_load_lds((const AS1 void*)(csrc[it] + k0),
                                             (AS3 void*)cdst[it], 16, 0, 0);
        __builtin_amdgcn_s_waitcnt(0);
        __syncthreads();

#pragma unroll
        for (int kc = 0; kc < 2; ++kc) {
            bf16x8 af[2], bfr[4];
#pragma unroll
            for (int i = 0; i < 2; ++i) af[i] = *(const bf16x8*)&lA[kc][(wave * 32 + i * 16 + l16) * 32 + quad * 8];
#pragma unroll
            for (int j = 0; j < 4; ++j) bfr[j] = *(const bf16x8*)&lB[kc][(j * 16 + l16) * 32 + quad * 8];
#pragma unroll
            for (int i = 0; i < 2; ++i)
#pragma unroll
                for (int j = 0; j < 4; ++j)
                    acc[i][j] = __builtin_amdgcn_mfma_f32_16x16x32_bf16(af[i], bfr[j], acc[i][j], 0, 0, 0);
        }
    }

    const int by = blockIdx.y;
    if (by < 40) {
        const float scale = (by < 32) ? 0.18033688011112042f : 1.0f;   // Q: 0.125*log2(e)
        __bf16* base = (by < 32) ? (Qr + (size_t)by * 2048 * 64)
                                 : (Kr + (size_t)(by - 32) * 2048 * 64);
#pragma unroll
        for (int jj = 0; jj < 2; ++jj) {
            const int dlo = jj * 16 + l16;
            const float inv = __builtin_amdgcn_exp2f(-(float)dlo * 0.41524101186092029f);
#pragma unroll
            for (int i = 0; i < 2; ++i)
#pragma unroll
                for (int r = 0; r < 4; ++r) {
                    const int s = m0 + wave * 32 + i * 16 + quad * 4 + r;
                    float sn, cs;
                    __sincosf((float)s * inv, &sn, &cs);
                    const float lo = acc[i][jj][r], hv = acc[i][jj + 2][r];
                    base[(size_t)s * 64 + dlo]      = (__bf16)((lo * cs - hv * sn) * scale);
                    base[(size_t)s * 64 + dlo + 32] = (__bf16)((hv * cs + lo * sn) * scale);
                }
        }
    } else {
        __bf16* vb = Vt + (size_t)(by - 40) * 64 * 2048;
#pragma unroll
        for (int i = 0; i < 2; ++i)
#pragma unroll
            for (int j = 0; j < 4; ++j) {
                const int d = j * 16 + l16;
                const int s0 = m0 + wave * 32 + i * 16 + quad * 4;
                bf16x4 p;
#pragma unroll
                for (int r = 0; r < 4; ++r) p[r] = (__bf16)acc[i][j][r];
                *(bf16x4*)&vb[(size_t)d * 2048 + s0] = p;
            }
    }
}

// ------------------------------------------------- out-projection GEMM, BM=128, BN=128, split-K=2
// (measured-best config) grid (16,16,2) = 512 blocks = 2 barrier domains/CU.
__global__ __launch_bounds__(256) void gemm_bt_sk(const __bf16* __restrict__ A, const __bf16* __restrict__ Bt,
                                                  float* __restrict__ C0, float* __restrict__ C1,
                                                  int M, int N, int K) {
    __shared__ __align__(16) __bf16 lA[128 * 32];
    __shared__ __align__(16) __bf16 lB[128 * 32];
    const int tid = threadIdx.x;
    const int wave = tid >> 6, lane = tid & 63;
    const int quad = lane >> 4, l16 = lane & 15;
    const int m0 = blockIdx.x * 128, n0 = blockIdx.y * 128;
    const int kz = blockIdx.z;
    const int kbeg = kz * (K >> 1), kend = kbeg + (K >> 1);
    float* C = kz ? C1 : C0;
    const int wm = (wave >> 1) * 64, wn = (wave & 1) * 64;
    fx4 acc[4][4] = {};

    const int st0 = wave * 1024;
    const int st1 = 4096 + wave * 1024;
    const int r0 = (st0 + lane * 16) >> 6, c0 = ((st0 + lane * 16) & 63) >> 1;
    const int r1 = (st1 + lane * 16) >> 6, c1 = ((st1 + lane * 16) & 63) >> 1;

    for (int k0 = kbeg; k0 < kend; k0 += 32) {
        __syncthreads();
        __builtin_amdgcn_global_load_lds((const AS1 void*)(A + (size_t)(m0 + r0) * K + k0 + c0),
                                         (AS3 void*)(lA + (st0 >> 1)), 16, 0, 0);
        __builtin_amdgcn_global_load_lds((const AS1 void*)(A + (size_t)(m0 + r1) * K + k0 + c1),
                                         (AS3 void*)(lA + (st1 >> 1)), 16, 0, 0);
        __builtin_amdgcn_global_load_lds((const AS1 void*)(Bt + (size_t)(n0 + r0) * K + k0 + c0),
                                         (AS3 void*)(lB + (st0 >> 1)), 16, 0, 0);
        __builtin_amdgcn_global_load_lds((const AS1 void*)(Bt + (size_t)(n0 + r1) * K + k0 + c1),
                                         (AS3 void*)(lB + (st1 >> 1)), 16, 0, 0);
        __builtin_amdgcn_s_waitcnt(0);
        __syncthreads();

        bf16x8 af[4], bfr[4];
#pragma unroll
        for (int i = 0; i < 4; ++i) af[i] = *(const bf16x8*)&lA[(wm + i * 16 + l16) * 32 + quad * 8];
#pragma unroll
        for (int j = 0; j < 4; ++j) bfr[j] = *(const bf16x8*)&lB[(wn + j * 16 + l16) * 32 + quad * 8];
#pragma unroll
        for (int i = 0; i < 4; ++i)
#pragma unroll
            for (int j = 0; j < 4; ++j)
                acc[i][j] = __builtin_amdgcn_mfma_f32_16x16x32_bf16(af[i], bfr[j], acc[i][j], 0, 0, 0);
    }
#pragma unroll
    for (int i = 0; i < 4; ++i)
#pragma unroll
        for (int j = 0; j < 4; ++j) {
            const int row = m0 + wm + i * 16 + quad * 4;
            const int col = n0 + wn + j * 16 + l16;
#pragma unroll
            for (int r = 0; r < 4; ++r)
                C[(size_t)(row + r) * N + col] = acc[i][j][r];
        }
}

// ------------------------------------------------- out += partial (deterministic split-K reduce)
__global__ __launch_bounds__(256) void reduce_add(float4* __restrict__ out, const float4* __restrict__ p) {
    const int i = blockIdx.x * 256 + threadIdx.x;
    float4 a = out[i];
    const float4 b = p[i];
    a.x += b.x; a.y += b.y; a.z += b.z; a.w += b.w;
    out[i] = a;
}

// ------------------------------------------------- flash attention: no-P-LDS + 8-wave split-K + LDS dbuf
// (R8 version, verified 44.9 us -- structural plateau, accepted.)
__global__ __launch_bounds__(512, 4) void flash_attn(const __bf16* __restrict__ Qr, const __bf16* __restrict__ Kr,
                                                     const __bf16* __restrict__ Vt, __bf16* __restrict__ O) {
    constexpr int S = 2048;
    __shared__ __align__(16) __bf16 smem[2][4 * 64 * 72];   // 73728 B, 2 buffers
    const int qt = blockIdx.x, h = blockIdx.y, kvh = h >> 2;
    const int tid = threadIdx.x, wave = tid >> 6, lane = tid & 63;
    const int grp = wave >> 2, w4 = wave & 3;
    const int l32 = lane & 31, hi = lane >> 5;
    const int goff = grp * 2 * 4608;

    const int qrow = qt * 128 + w4 * 32 + l32;
    const __bf16* qptr = Qr + ((size_t)h * S + qrow) * 64;
    bf16x8 qf[4];
#pragma unroll
    for (int kc = 0; kc < 4; ++kc) qf[kc] = *(const bf16x8*)(qptr + kc * 16 + hi * 8);

    const __bf16* Kbase = Kr + (size_t)kvh * S * 64;
    const __bf16* Vbase = Vt + (size_t)kvh * 64 * S;

    const int gtid = tid & 255;
    const int krow = gtid >> 3;
    const int kcol = (gtid & 7) * 8;
    const int vslot = (kcol & 48) | ((kcol & 8) >> 1);

    bf16x8 kreg0 = *(const bf16x8*)(Kbase + (size_t)(grp * 64 + krow) * 64 + kcol);
    bf16x8 kreg1 = *(const bf16x8*)(Kbase + (size_t)(grp * 64 + 32 + krow) * 64 + kcol);
    bf16x8 vreg0 = *(const bf16x8*)(Vbase + (size_t)krow * S + grp * 64 + kcol);
    bf16x8 vreg1 = *(const bf16x8*)(Vbase + (size_t)(32 + krow) * S + grp * 64 + kcol);

    fx16 ov0, ov1;
#pragma unroll
    for (int i = 0; i < 16; ++i) { ov0[i] = 0.f; ov1[i] = 0.f; }
    float l_acc = 0.f;

    {
        __bf16* nK = &smem[0][goff];
        __bf16* nV = nK + 4608;
        *(bf16x8*)&nK[krow * 72 + kcol] = kreg0;
        *(bf16x8*)&nK[(32 + krow) * 72 + kcol] = kreg1;
        bf16x4 v0lo = { vreg0[0], vreg0[1], vreg0[2], vreg0[3] };
        bf16x4 v0hi = { vreg0[4], vreg0[5], vreg0[6], vreg0[7] };
        bf16x4 v1lo = { vreg1[0], vreg1[1], vreg1[2], vreg1[3] };
        bf16x4 v1hi = { vreg1[4], vreg1[5], vreg1[6], vreg1[7] };
        *(bf16x4*)&nV[krow * 72 + vslot]            = v0lo;
        *(bf16x4*)&nV[krow * 72 + vslot + 8]        = v0hi;
        *(bf16x4*)&nV[(32 + krow) * 72 + vslot]     = v1lo;
        *(bf16x4*)&nV[(32 + krow) * 72 + vslot + 8] = v1hi;
        const int kt1 = 2 + grp;
        kreg0 = *(const bf16x8*)(Kbase + (size_t)(kt1 * 64 + krow) * 64 + kcol);
        kreg1 = *(const bf16x8*)(Kbase + (size_t)(kt1 * 64 + 32 + krow) * 64 + kcol);
        vreg0 = *(const bf16x8*)(Vbase + (size_t)krow * S + kt1 * 64 + kcol);
        vreg1 = *(const bf16x8*)(Vbase + (size_t)(32 + krow) * S + kt1 * 64 + kcol);
    }
    __syncthreads();

    for (int it = 0; it < 16; ++it) {
        __bf16* lKg = &smem[it & 1][goff];
        __bf16* lVg = lKg + 4608;

        if (it + 1 < 16) {
            __bf16* nK = &smem[(it + 1) & 1][goff];
            __bf16* nV = nK + 4608;
            *(bf16x8*)&nK[krow * 72 + kcol] = kreg0;
            *(bf16x8*)&nK[(32 + krow) * 72 + kcol] = kreg1;
            bf16x4 v0lo = { vreg0[0], vreg0[1], vreg0[2], vreg0[3] };
            bf16x4 v0hi = { vreg0[4], vreg0[5], vreg0[6], vreg0[7] };
            bf16x4 v1lo = { vreg1[0], vreg1[1], vreg1[2], vreg1[3] };
            bf16x4 v1hi = { vreg1[4], vreg1[5], vreg1[6], vreg1[7] };
            *(bf16x4*)&nV[krow * 72 + vslot]            = v0lo;
            *(bf16x4*)&nV[krow * 72 + vslot + 8]        = v0hi;
            *(bf16x4*)&nV[(32 + krow) * 72 + vslot]     = v1lo;
            *(bf16x4*)&nV[(32 + krow) * 72 + vslot + 8] = v1hi;
            const int it2 = (it + 2 < 16) ? it + 2 : 15;
            const int ktn = it2 * 2 + grp;
            kreg0 = *(const bf16x8*)(Kbase + (size_t)(ktn * 64 + krow) * 64 + kcol);
            kreg1 = *(const bf16x8*)(Kbase + (size_t)(ktn * 64 + 32 + krow) * 64 + kcol);
            vreg0 = *(const bf16x8*)(Vbase + (size_t)krow * S + ktn * 64 + kcol);
            vreg1 = *(const bf16x8*)(Vbase + (size_t)(32 + krow) * S + ktn * 64 + kcol);
        }

        fx16 sc0, sc1;
#pragma unroll
        for (int i = 0; i < 16; ++i) { sc0[i] = 0.f; sc1[i] = 0.f; }
#pragma unroll
        for (int kc = 0; kc < 4; ++kc) {
            const bf16x8 a0 = *(const bf16x8*)&lKg[l32 * 72 + kc * 16 + hi * 8];
            const bf16x8 a1 = *(const bf16x8*)&lKg[(32 + l32) * 72 + kc * 16 + hi * 8];
            sc0 = __builtin_amdgcn_mfma_f32_32x32x16_bf16(a0, qf[kc], sc0, 0, 0, 0);
            sc1 = __builtin_amdgcn_mfma_f32_32x32x16_bf16(a1, qf[kc], sc1, 0, 0, 0);
        }

#pragma unroll
        for (int h2 = 0; h2 < 2; ++h2) {
#pragma unroll
            for (int c = 0; c < 2; ++c) {
                bf16x8 pb;
#pragma unroll
                for (int j = 0; j < 8; ++j) {
                    const float sv = h2 ? sc1[c * 8 + j] : sc0[c * 8 + j];
                    const float p = __builtin_amdgcn_exp2f(sv);
                    l_acc += p;
                    pb[j] = (__bf16)p;
                }
                const int kcv = h2 * 2 + c;
                const bf16x8 va0 = *(const bf16x8*)&lVg[l32 * 72 + kcv * 16 + hi * 8];
                const bf16x8 va1 = *(const bf16x8*)&lVg[(32 + l32) * 72 + kcv * 16 + hi * 8];
                ov0 = __builtin_amdgcn_mfma_f32_32x32x16_bf16(va0, pb, ov0, 0, 0, 0);
                ov1 = __builtin_amdgcn_mfma_f32_32x32x16_bf16(va1, pb, ov1, 0, 0, 0);
            }
        }
        __syncthreads();
    }

    const float l_pair = l_acc + __shfl_xor(l_acc, 32, 64);

    fx4* lO = (fx4*)&smem[0][0];
    float* lL = (float*)(&smem[0][0] + 16384);   // byte 32768
    if (grp == 1) {
#pragma unroll
        for (int ic = 0; ic < 4; ++ic) {
            fx4 c0, c1;
#pragma unroll
            for (int r = 0; r < 4; ++r) { c0[r] = ov0[ic * 4 + r]; c1[r] = ov1[ic * 4 + r]; }
            lO[(ic * 4 + w4) * 64 + lane] = c0;
            lO[((ic + 4) * 4 + w4) * 64 + lane] = c1;
        }
        if (hi == 0) lL[w4 * 32 + l32] = l_pair;
    }
    __syncthreads();
    if (grp == 0) {
#pragma unroll
        for (int ic = 0; ic < 4; ++ic) {
            const fx4 c0 = lO[(ic * 4 + w4) * 64 + lane];
            const fx4 c1 = lO[((ic + 4) * 4 + w4) * 64 + lane];
#pragma unroll
            for (int r = 0; r < 4; ++r) { ov0[ic * 4 + r] += c0[r]; ov1[ic * 4 + r] += c1[r]; }
        }
        const float inv_l = 1.0f / (l_pair + lL[w4 * 32 + l32]);
#pragma unroll
        for (int dt = 0; dt < 2; ++dt)
#pragma unroll
            for (int rg2 = 0; rg2 < 4; ++rg2) {
                bf16x4 o4;
#pragma unroll
                for (int r = 0; r < 4; ++r)
                    o4[r] = (__bf16)((dt ? ov1[rg2 * 4 + r] : ov0[rg2 * 4 + r]) * inv_l);
                const int col = h * 64 + dt * 32 + rg2 * 8 + hi * 4;
                *(bf16x4*)(O + (size_t)qrow * 2048 + col) = o4;
            }
    }
}

// ----------------------------------------------------------------------------
extern "C" void kernel_launch(void* const* d_in, const int* in_sizes, int n_in,
                              void* d_out, int out_size, void* d_ws, size_t ws_size,
                              hipStream_t stream) {
    const float* x  = (const float*)d_in[0];
    const float* wq = (const float*)d_in[1];
    const float* wk = (const float*)d_in[2];
    const float* wv = (const float*)d_in[3];
    const float* wo = (const float*)d_in[4];
    float* out = (float*)d_out;
    char* ws = (char*)d_ws;

    __bf16* Xb    = (__bf16*)ws;                        // [0, 8M)
    __bf16* WqkvT = (__bf16*)(ws + ((size_t)8 << 20));  // [8M, 20M)  3072 x 2048
    __bf16* WoT   = (__bf16*)(ws + ((size_t)20 << 20)); // [20M, 28M) 2048 x 2048
    __bf16* Qr    = (__bf16*)(ws + ((size_t)28 << 20)); // [28M, 36M) 32 x 2048 x 64
    __bf16* Kr    = (__bf16*)(ws + ((size_t)36 << 20)); // [36M, 38M)  8 x 2048 x 64
    __bf16* Vt    = (__bf16*)(ws + ((size_t)38 << 20)); // [38M, 40M)  8 x 64 x 2048
    __bf16* Ob    = (__bf16*)(ws + ((size_t)40 << 20)); // [40M, 48M) 2048 x 2048
    float*  Cp    = (float*)ws;                         // [0, 16.8M) split-K partial (Xb/WqkvT dead)

    prep<<<14336, 256, 0, stream>>>((const float4*)x, Xb, wq, wk, wv, wo, WqkvT, WoT);
    gemm_qkv<<<dim3(16, 48), 256, 0, stream>>>(Xb, WqkvT, Qr, Kr, Vt);
    flash_attn<<<dim3(16, 32), 512, 0, stream>>>(Qr, Kr, Vt, Ob);
    gemm_bt_sk<<<dim3(16, 16, 2), 256, 0, stream>>>(Ob, WoT, out, Cp, 2048, 2048, 2048);
    reduce_add<<<4096, 256, 0, stream>>>((float4*)out, (const float4*)Cp);
}